// Round 1
// baseline (308.712 us; speedup 1.0000x reference)
//
#include <hip/hip_runtime.h>
#include <hip/hip_fp16.h>

typedef _Float16 f16;
typedef _Float16 f16x8 __attribute__((ext_vector_type(8)));
typedef _Float16 f16x4 __attribute__((ext_vector_type(4)));
typedef float    f32x4 __attribute__((ext_vector_type(4)));

#define DEV __device__ __forceinline__

DEV int imin(int a, int b) { return a < b ? a : b; }

// ---------------------------------------------------------------------------
// Problem constants
//   B=16, N=1044 (padded 1088 in q/k/v, 1056 in o), DIM=512, H=8, KD=32, D=64
//   qkv channels 1024, IMG=1024 (32x32), out (16,1024,512) fp32
// ---------------------------------------------------------------------------

// workspace offsets (bytes, all 256-aligned)
constexpr size_t OFF_XH   = 0;            // x fp16            16704*512*2 = 17,104,896
constexpr size_t OFF_WQ   = 17104896;     // qkv_w fp16        1024*512*2
constexpr size_t OFF_PW   = 18153472;     // proj_w fp16 pad   1024*1056*2
constexpr size_t OFF_OW   = 20316160;     // out_w fp16        512*512*2
constexpr size_t OFF_BNA  = 20840448;     // bn scale fp32     1024*4
constexpr size_t OFF_BNB  = 20844544;     // bn shift fp32     1024*4
constexpr size_t OFF_QB   = 20848640;     // q fp16 (128,1088,32)
constexpr size_t OFF_KB   = 29761536;     // k fp16 (128,1088,32)
constexpr size_t OFF_VB   = 38674432;     // v fp16 (128,1088,64)
constexpr size_t OFF_OPAD = 56500224;     // o fp16 (16,512,1056)
constexpr size_t OFF_VCT  = 73801728;     // vcT fp32 (16,1024,512)
constexpr size_t OFF_XOT  = 107356160;    // xoT fp16 (16,1024,512)

// ---------------------------------------------------------------------------
// prep: fp32->fp16 conversions, BN fold, zero pads
// ---------------------------------------------------------------------------
__global__ __launch_bounds__(256) void prep_kernel(
    const float* __restrict__ x, const float* __restrict__ qkv_w,
    const float* __restrict__ bn_g, const float* __restrict__ bn_b,
    const float* __restrict__ bn_m, const float* __restrict__ bn_v,
    const float* __restrict__ proj_w, const float* __restrict__ out_w,
    f16* __restrict__ x_h, f16* __restrict__ wq_h, f16* __restrict__ pw_h,
    f16* __restrict__ ow_h, float* __restrict__ bn_a, float* __restrict__ bn_sh,
    f16* __restrict__ qb, f16* __restrict__ kb, f16* __restrict__ vb,
    f16* __restrict__ opad)
{
  long tid = (long)blockIdx.x * blockDim.x + threadIdx.x;
  long gsz = (long)gridDim.x * blockDim.x;

  // x: 16704*512 = 8,552,448 floats, vectorized by 4
  for (long i = tid; i < 2138112; i += gsz) {
    float4 f = ((const float4*)x)[i];
    f16x4 o = {(f16)f.x, (f16)f.y, (f16)f.z, (f16)f.w};
    ((f16x4*)x_h)[i] = o;
  }
  for (long i = tid; i < 524288; i += gsz) wq_h[i] = (f16)qkv_w[i];
  // proj_w (1024,1044) -> padded (1024,1056)
  for (long i = tid; i < 1081344; i += gsz) {
    long m = i / 1056, nn = i - m * 1056;
    pw_h[i] = (nn < 1044) ? (f16)proj_w[m * 1044 + nn] : (f16)0.f;
  }
  for (long i = tid; i < 262144; i += gsz) ow_h[i] = (f16)out_w[i];
  for (long i = tid; i < 1024; i += gsz) {
    float a = bn_g[i] * rsqrtf(bn_v[i] + 1e-5f);
    bn_a[i] = a;
    bn_sh[i] = bn_b[i] - bn_m[i] * a;
  }
  // q/k/v pad rows 1044..1087 for each of 128 (b,h)
  for (long i = tid; i < 5632; i += gsz) {
    int bh = (int)(i / 44);
    int nn = 1044 + (int)(i - (long)bh * 44);
    f16* q = qb + ((long)bh * 1088 + nn) * 32;
    f16* k = kb + ((long)bh * 1088 + nn) * 32;
    f16* v = vb + ((long)bh * 1088 + nn) * 64;
    for (int j = 0; j < 32; ++j) { q[j] = (f16)0.f; k[j] = (f16)0.f; }
    for (int j = 0; j < 64; ++j) v[j] = (f16)0.f;
  }
  // o_pad cols 1044..1055 for each (b,c)
  for (long i = tid; i < 8192; i += gsz) {
    f16* o = opad + i * 1056 + 1044;
    for (int j = 0; j < 12; ++j) o[j] = (f16)0.f;
  }
}

// ---------------------------------------------------------------------------
// shared 128x128x(K) NT-GEMM core: A(M,K) row-major, B(N,K) row-major,
// C[i][j] = sum_k A[i,k]*B[j,k].  256 threads = 4 waves (2x2), 64x64/wave,
// BK=32, LDS stride 40 fp16 (2-way bank conflict = free).
// ---------------------------------------------------------------------------
DEV void gemm_core(const f16* __restrict__ A, const f16* __restrict__ B,
                   int lda, int ldb, int kIters, int rowClamp,
                   f16* As, f16* Bs, f32x4 acc[4][4])
{
  const int t = threadIdx.x;
  const int wave = t >> 6, lane = t & 63;
  const int wr = wave >> 1, wc = wave & 1;
  const int r0 = t >> 2, seg = t & 3;
  const int fr = lane & 15, fg = lane >> 4;
  const int ra0 = imin(r0, rowClamp);
  const int ra1 = imin(r0 + 64, rowClamp);
  for (int kt = 0; kt < kIters; ++kt) {
    const int kb = kt * 32 + seg * 8;
    f16x8 a0 = *(const f16x8*)(A + (long)ra0 * lda + kb);
    f16x8 a1 = *(const f16x8*)(A + (long)ra1 * lda + kb);
    f16x8 b0 = *(const f16x8*)(B + (long)r0 * ldb + kb);
    f16x8 b1 = *(const f16x8*)(B + (long)(r0 + 64) * ldb + kb);
    __syncthreads();
    *(f16x8*)(As + r0 * 40 + seg * 8) = a0;
    *(f16x8*)(As + (r0 + 64) * 40 + seg * 8) = a1;
    *(f16x8*)(Bs + r0 * 40 + seg * 8) = b0;
    *(f16x8*)(Bs + (r0 + 64) * 40 + seg * 8) = b1;
    __syncthreads();
    f16x8 af[4], bf[4];
    #pragma unroll
    for (int m = 0; m < 4; ++m)
      af[m] = *(const f16x8*)(As + (wr * 64 + m * 16 + fr) * 40 + fg * 8);
    #pragma unroll
    for (int n = 0; n < 4; ++n)
      bf[n] = *(const f16x8*)(Bs + (wc * 64 + n * 16 + fr) * 40 + fg * 8);
    #pragma unroll
    for (int m = 0; m < 4; ++m)
      #pragma unroll
      for (int n = 0; n < 4; ++n)
        acc[m][n] = __builtin_amdgcn_mfma_f32_16x16x32_f16(af[m], bf[n], acc[m][n], 0, 0, 0);
  }
}

// ---------------------------------------------------------------------------
// QKV GEMM + BN epilogue -> q/k/v fp16 buffers (q pre-scaled by 32^-0.5)
// grid (8, 131): cols 1024, rows 16704 (tail-guarded)
// ---------------------------------------------------------------------------
__global__ __launch_bounds__(256) void qkv_gemm(
    const f16* __restrict__ x_h, const f16* __restrict__ wq,
    const float* __restrict__ bn_a, const float* __restrict__ bn_sh,
    f16* __restrict__ qb, f16* __restrict__ kb, f16* __restrict__ vb)
{
  __shared__ f16 As[128 * 40];
  __shared__ f16 Bs[128 * 40];
  const int row0 = blockIdx.y * 128, col0 = blockIdx.x * 128;
  f32x4 acc[4][4];
  #pragma unroll
  for (int m = 0; m < 4; ++m)
    #pragma unroll
    for (int n = 0; n < 4; ++n) acc[m][n] = (f32x4){0.f, 0.f, 0.f, 0.f};
  gemm_core(x_h + (long)row0 * 512, wq + (long)col0 * 512, 512, 512, 16,
            16703 - row0, As, Bs, acc);
  const int lane = threadIdx.x & 63, wave = threadIdx.x >> 6;
  const int wr = wave >> 1, wc = wave & 1, fr = lane & 15, fg = lane >> 4;
  float ba[4], bsh[4];
  int chs[4];
  #pragma unroll
  for (int n = 0; n < 4; ++n) {
    int ch = col0 + wc * 64 + n * 16 + fr;
    chs[n] = ch; ba[n] = bn_a[ch]; bsh[n] = bn_sh[ch];
  }
  #pragma unroll
  for (int m = 0; m < 4; ++m) {
    #pragma unroll
    for (int rr = 0; rr < 4; ++rr) {
      int row = row0 + wr * 64 + m * 16 + fg * 4 + rr;
      if (row < 16704) {
        int bi = row / 1044;
        int ni = row - bi * 1044;
        #pragma unroll
        for (int n = 0; n < 4; ++n) {
          float val = acc[m][n][rr] * ba[n] + bsh[n];
          int ch = chs[n];
          int hh = ch >> 7, r = ch & 127;
          long base = (long)(bi * 8 + hh) * 1088 + ni;
          if (r < 32)      qb[base * 32 + r] = (f16)(val * 0.17677669529663687f);
          else if (r < 64) kb[base * 32 + (r - 32)] = (f16)val;
          else             vb[base * 64 + (r - 64)] = (f16)val;
        }
      }
    }
  }
}

// ---------------------------------------------------------------------------
// depthwise conv branch.  torch raw reshape: channel c (=h*64+ci), pixel
// p=s1*32+s2 comes from v[b,h, n=ci*16+(s1>>1), d=(s1&1)*32+s2].
// 16 channels per block; writes vcT[b][p][c] fp32 (transposed for proj).
// grid (32, 16)
// ---------------------------------------------------------------------------
__global__ __launch_bounds__(256) void conv_kernel(
    const f16* __restrict__ vb, const float* __restrict__ conv_w,
    const float* __restrict__ conv_b, float* __restrict__ vcT)
{
  __shared__ f16 img[16][34][36];
  const int b = blockIdx.y, g = blockIdx.x;
  const int c0 = g * 16, h = c0 >> 6, ci0 = c0 & 63;
  const int t = threadIdx.x;
  for (int i = t; i < 16 * 34 * 36; i += 256) ((f16*)img)[i] = (f16)0.f;
  __syncthreads();
  // load 256 v-rows (16 channels x 16 rows), hardswish, place into images
  const f16* src = vb + ((long)(b * 8 + h) * 1088 + ci0 * 16) * 64;
  const int cl_ld = t >> 4, r16 = t & 15;
  #pragma unroll
  for (int j = 0; j < 8; ++j) {
    f16x8 vv = *(const f16x8*)(src + (long)t * 64 + j * 8);
    #pragma unroll
    for (int e = 0; e < 8; ++e) {
      int d = j * 8 + e;
      float xv = (float)vv[e];
      float hs = xv * fminf(fmaxf(xv + 3.f, 0.f), 6.f) * (1.f / 6.f);
      int s1 = r16 * 2 + (d >> 5), s2 = d & 31;
      img[cl_ld][1 + s1][1 + s2] = (f16)hs;
    }
  }
  __syncthreads();
  const int cl = t & 15, pg = t >> 4;
  const int c = c0 + cl;
  float w[9];
  #pragma unroll
  for (int i = 0; i < 9; ++i) w[i] = conv_w[c * 9 + i];
  const float bias = conv_b[c];
  for (int i = 0; i < 64; ++i) {
    int p = pg + i * 16;
    int s1 = p >> 5, s2 = p & 31;
    float a = bias;
    #pragma unroll
    for (int di = 0; di < 3; ++di)
      #pragma unroll
      for (int dj = 0; dj < 3; ++dj)
        a += w[di * 3 + dj] * (float)img[cl][s1 + di][s2 + dj];
    vcT[((long)b * 1024 + p) * 512 + c] = a;
  }
}

// ---------------------------------------------------------------------------
// fused flash attention.  4 waves x 16 queries; 33 key-tiles of 32.
// Scatters o through the torch raw reshape into opad (16,512,1056) fp16.
// grid (17, 128)
// ---------------------------------------------------------------------------
__global__ __launch_bounds__(256) void attn_kernel(
    const f16* __restrict__ qb, const f16* __restrict__ kb,
    const f16* __restrict__ vb, f16* __restrict__ opad)
{
  __shared__ f16 VT[64 * 40];     // V^T tile: [d][k], stride 40
  __shared__ f16 P[4][16 * 40];   // per-wave P: [q][k], stride 40
  const int bh = blockIdx.y;
  const int b = bh >> 3, h = bh & 7;
  const int wave = threadIdx.x >> 6, lane = threadIdx.x & 63;
  const int fr = lane & 15, fg = lane >> 4;
  const int q0 = blockIdx.x * 64 + wave * 16;
  const f16* qbase = qb + (long)bh * 1088 * 32;
  const f16* kbase = kb + (long)bh * 1088 * 32;
  const f16* vbase = vb + (long)bh * 1088 * 64;

  f16x8 qf = *(const f16x8*)(qbase + (long)(q0 + fr) * 32 + fg * 8);
  f32x4 o_acc[4];
  #pragma unroll
  for (int n = 0; n < 4; ++n) o_acc[n] = (f32x4){0.f, 0.f, 0.f, 0.f};
  float mrow[4], lrow[4];
  #pragma unroll
  for (int r = 0; r < 4; ++r) { mrow[r] = -1e30f; lrow[r] = 0.f; }

  for (int kt = 0; kt < 33; ++kt) {
    __syncthreads();
    {
      int kl = threadIdx.x & 31, d0 = (threadIdx.x >> 5) * 8;
      f16x8 vv = *(const f16x8*)(vbase + (long)(kt * 32 + kl) * 64 + d0);
      #pragma unroll
      for (int j = 0; j < 8; ++j) VT[(d0 + j) * 40 + kl] = vv[j];
    }
    __syncthreads();
    f16x8 kf0 = *(const f16x8*)(kbase + (long)(kt * 32 + fr) * 32 + fg * 8);
    f16x8 kf1 = *(const f16x8*)(kbase + (long)(kt * 32 + 16 + fr) * 32 + fg * 8);
    f32x4 s0 = __builtin_amdgcn_mfma_f32_16x16x32_f16(qf, kf0, (f32x4){0.f,0.f,0.f,0.f}, 0, 0, 0);
    f32x4 s1 = __builtin_amdgcn_mfma_f32_16x16x32_f16(qf, kf1, (f32x4){0.f,0.f,0.f,0.f}, 0, 0, 0);
    const int kg0 = kt * 32 + fr, kg1 = kt * 32 + 16 + fr;
    if (kg0 >= 1044) {
      #pragma unroll
      for (int r = 0; r < 4; ++r) s0[r] = -1e30f;
    }
    if (kg1 >= 1044) {
      #pragma unroll
      for (int r = 0; r < 4; ++r) s1[r] = -1e30f;
    }
    float tmax[4];
    #pragma unroll
    for (int r = 0; r < 4; ++r) tmax[r] = fmaxf(s0[r], s1[r]);
    #pragma unroll
    for (int off = 1; off < 16; off <<= 1)
      #pragma unroll
      for (int r = 0; r < 4; ++r) tmax[r] = fmaxf(tmax[r], __shfl_xor(tmax[r], off));
    float alpha[4], p0[4], p1[4], psum[4];
    #pragma unroll
    for (int r = 0; r < 4; ++r) {
      float mn = fmaxf(mrow[r], tmax[r]);
      alpha[r] = __expf(mrow[r] - mn);
      mrow[r] = mn;
      p0[r] = __expf(s0[r] - mn);
      p1[r] = __expf(s1[r] - mn);
      psum[r] = p0[r] + p1[r];
    }
    #pragma unroll
    for (int off = 1; off < 16; off <<= 1)
      #pragma unroll
      for (int r = 0; r < 4; ++r) psum[r] += __shfl_xor(psum[r], off);
    #pragma unroll
    for (int r = 0; r < 4; ++r) lrow[r] = lrow[r] * alpha[r] + psum[r];
    // write P (fp16) and rescale O
    #pragma unroll
    for (int r = 0; r < 4; ++r) {
      P[wave][(fg * 4 + r) * 40 + fr]      = (f16)p0[r];
      P[wave][(fg * 4 + r) * 40 + 16 + fr] = (f16)p1[r];
    }
    #pragma unroll
    for (int n = 0; n < 4; ++n)
      #pragma unroll
      for (int r = 0; r < 4; ++r) o_acc[n][r] *= alpha[r];
    f16x8 pa = *(const f16x8*)(&P[wave][fr * 40 + fg * 8]);
    #pragma unroll
    for (int n = 0; n < 4; ++n) {
      f16x8 vf = *(const f16x8*)(VT + (n * 16 + fr) * 40 + fg * 8);
      o_acc[n] = __builtin_amdgcn_mfma_f32_16x16x32_f16(pa, vf, o_acc[n], 0, 0, 0);
    }
  }
  // epilogue: normalize + scatter via flat = q*512 + h*64 + d -> (c, n')
  #pragma unroll
  for (int n = 0; n < 4; ++n) {
    #pragma unroll
    for (int r = 0; r < 4; ++r) {
      int q = q0 + fg * 4 + r;
      if (q < 1044) {
        float val = o_acc[n][r] / lrow[r];
        int d = n * 16 + fr;
        unsigned flat = (unsigned)q * 512u + (unsigned)h * 64u + (unsigned)d;
        unsigned c = flat / 1044u;
        unsigned np = flat - c * 1044u;
        opad[((long)b * 512 + c) * 1056 + np] = (f16)val;
      }
    }
  }
}

// ---------------------------------------------------------------------------
// proj GEMM: C[m,c] = sum_n' pw[m,n'] * o[c,n']  (+proj_b[m] + vcT[b][m][c])
// -> xoT[b][m][c] fp16.  grid (4, 8, 16)
// ---------------------------------------------------------------------------
__global__ __launch_bounds__(256) void proj_gemm(
    const f16* __restrict__ pw, const f16* __restrict__ opad,
    const float* __restrict__ proj_b, const float* __restrict__ vcT,
    f16* __restrict__ xoT)
{
  __shared__ f16 As[128 * 40];
  __shared__ f16 Bs[128 * 40];
  const int b = blockIdx.z;
  const int row0 = blockIdx.y * 128;  // m (image pixel)
  const int col0 = blockIdx.x * 128;  // c (channel)
  f32x4 acc[4][4];
  #pragma unroll
  for (int m = 0; m < 4; ++m)
    #pragma unroll
    for (int n = 0; n < 4; ++n) acc[m][n] = (f32x4){0.f, 0.f, 0.f, 0.f};
  gemm_core(pw + (long)row0 * 1056, opad + ((long)b * 512 + col0) * 1056,
            1056, 1056, 33, 1 << 30, As, Bs, acc);
  const int lane = threadIdx.x & 63, wave = threadIdx.x >> 6;
  const int wr = wave >> 1, wc = wave & 1, fr = lane & 15, fg = lane >> 4;
  #pragma unroll
  for (int m = 0; m < 4; ++m) {
    #pragma unroll
    for (int rr = 0; rr < 4; ++rr) {
      int mi = row0 + wr * 64 + m * 16 + fg * 4 + rr;
      float pb = proj_b[mi];
      #pragma unroll
      for (int n = 0; n < 4; ++n) {
        int c = col0 + wc * 64 + n * 16 + fr;
        long idx = ((long)b * 1024 + mi) * 512 + c;
        xoT[idx] = (f16)(acc[m][n][rr] + pb + vcT[idx]);
      }
    }
  }
}

// ---------------------------------------------------------------------------
// out GEMM: out[b,m,co] = sum_c xoT[b,m,c]*ow[co,c] + out_b[co]  (fp32 out)
// grid (4, 8, 16)
// ---------------------------------------------------------------------------
__global__ __launch_bounds__(256) void out_gemm(
    const f16* __restrict__ xoT, const f16* __restrict__ ow,
    const float* __restrict__ out_b, float* __restrict__ out)
{
  __shared__ f16 As[128 * 40];
  __shared__ f16 Bs[128 * 40];
  const int b = blockIdx.z;
  const int row0 = blockIdx.y * 128;  // m
  const int col0 = blockIdx.x * 128;  // co
  f32x4 acc[4][4];
  #pragma unroll
  for (int m = 0; m < 4; ++m)
    #pragma unroll
    for (int n = 0; n < 4; ++n) acc[m][n] = (f32x4){0.f, 0.f, 0.f, 0.f};
  gemm_core(xoT + ((long)b * 1024 + row0) * 512, ow + (long)col0 * 512,
            512, 512, 16, 1 << 30, As, Bs, acc);
  const int lane = threadIdx.x & 63, wave = threadIdx.x >> 6;
  const int wr = wave >> 1, wc = wave & 1, fr = lane & 15, fg = lane >> 4;
  float ob[4];
  #pragma unroll
  for (int n = 0; n < 4; ++n) ob[n] = out_b[col0 + wc * 64 + n * 16 + fr];
  #pragma unroll
  for (int m = 0; m < 4; ++m) {
    #pragma unroll
    for (int rr = 0; rr < 4; ++rr) {
      int mi = row0 + wr * 64 + m * 16 + fg * 4 + rr;
      #pragma unroll
      for (int n = 0; n < 4; ++n) {
        int co = col0 + wc * 64 + n * 16 + fr;
        out[((long)b * 1024 + mi) * 512 + co] = acc[m][n][rr] + ob[n];
      }
    }
  }
}

// ---------------------------------------------------------------------------
extern "C" void kernel_launch(void* const* d_in, const int* in_sizes, int n_in,
                              void* d_out, int out_size, void* d_ws, size_t ws_size,
                              hipStream_t stream) {
  const float* x      = (const float*)d_in[0];
  const float* qkv_w  = (const float*)d_in[1];
  const float* bn_g   = (const float*)d_in[2];
  const float* bn_b   = (const float*)d_in[3];
  const float* bn_m   = (const float*)d_in[4];
  const float* bn_v   = (const float*)d_in[5];
  const float* conv_w = (const float*)d_in[6];
  const float* conv_b = (const float*)d_in[7];
  const float* proj_w = (const float*)d_in[8];
  const float* proj_b = (const float*)d_in[9];
  const float* out_w  = (const float*)d_in[10];
  const float* out_b  = (const float*)d_in[11];
  float* out = (float*)d_out;

  char* ws = (char*)d_ws;
  f16*   x_h   = (f16*)(ws + OFF_XH);
  f16*   wq_h  = (f16*)(ws + OFF_WQ);
  f16*   pw_h  = (f16*)(ws + OFF_PW);
  f16*   ow_h  = (f16*)(ws + OFF_OW);
  float* bn_a  = (float*)(ws + OFF_BNA);
  float* bn_sh = (float*)(ws + OFF_BNB);
  f16*   qb    = (f16*)(ws + OFF_QB);
  f16*   kb    = (f16*)(ws + OFF_KB);
  f16*   vb    = (f16*)(ws + OFF_VB);
  f16*   opad  = (f16*)(ws + OFF_OPAD);
  float* vcT   = (float*)(ws + OFF_VCT);
  f16*   xoT   = (f16*)(ws + OFF_XOT);

  prep_kernel<<<1024, 256, 0, stream>>>(x, qkv_w, bn_g, bn_b, bn_m, bn_v,
                                        proj_w, out_w, x_h, wq_h, pw_h, ow_h,
                                        bn_a, bn_sh, qb, kb, vb, opad);
  qkv_gemm<<<dim3(8, 131), 256, 0, stream>>>(x_h, wq_h, bn_a, bn_sh, qb, kb, vb);
  conv_kernel<<<dim3(32, 16), 256, 0, stream>>>(vb, conv_w, conv_b, vcT);
  attn_kernel<<<dim3(17, 128), 256, 0, stream>>>(qb, kb, vb, opad);
  proj_gemm<<<dim3(4, 8, 16), 256, 0, stream>>>(pw_h, opad, proj_b, vcT, xoT);
  out_gemm<<<dim3(4, 8, 16), 256, 0, stream>>>(xoT, ow_h, out_b, out);
}

// Round 2
// 238.521 us; speedup vs baseline: 1.2943x; 1.2943x over previous
//
#include <hip/hip_runtime.h>
#include <hip/hip_fp16.h>

typedef _Float16 f16;
typedef _Float16 f16x8 __attribute__((ext_vector_type(8)));
typedef _Float16 f16x4 __attribute__((ext_vector_type(4)));
typedef _Float16 f16x2 __attribute__((ext_vector_type(2)));
typedef float    f32x4 __attribute__((ext_vector_type(4)));
typedef float    f32x16 __attribute__((ext_vector_type(16)));

#define DEV __device__ __forceinline__

DEV int imin(int a, int b) { return a < b ? a : b; }

#if defined(__has_builtin)
#  if __has_builtin(__builtin_amdgcn_exp2f)
#    define EXP2(x) __builtin_amdgcn_exp2f(x)
#  else
#    define EXP2(x) __expf((x) * 0.6931471805599453f)
#  endif
#else
#  define EXP2(x) __expf((x) * 0.6931471805599453f)
#endif

// q pre-scale: (1/sqrt(32)) * log2(e) so softmax is p = 2^s
#define QSCALE (0.17677669529663687f * 1.4426950408889634f)

// ---------------------------------------------------------------------------
// Problem constants: B=16, N=1044, DIM=512, H=8, KD=32, D=64
// q padded to 1152 rows, k/v to 1088, o cols to 1056
// ---------------------------------------------------------------------------

// workspace offsets (bytes)
constexpr size_t OFF_XH   = 0;            // x fp16 (16704,512)          17,104,896
constexpr size_t OFF_WQ   = 17104896;     // qkv_w fp16 (1024,512)        1,048,576
constexpr size_t OFF_PW   = 18153472;     // proj_w fp16 (1024,1056)      2,162,688
constexpr size_t OFF_OW   = 20316160;     // out_w fp16 (512,512)           524,288
constexpr size_t OFF_BNA  = 20840448;     // bn scale fp32 (1024)
constexpr size_t OFF_BNB  = 20844544;     // bn shift fp32 (1024)
constexpr size_t OFF_QB   = 20848640;     // q fp16 (128,1152,32)         9,437,184
constexpr size_t OFF_KB   = 30285824;     // k fp16 (128,1088,32)         8,912,896
constexpr size_t OFF_VT   = 39198720;     // v^T fp16 (128,64,1088)      17,825,792
constexpr size_t OFF_OPAD = 57024512;     // o fp16 (16,512,1056)        17,301,504
constexpr size_t OFF_VCT  = 74326016;     // vcT fp16 (16,1024,512)      16,777,216
constexpr size_t OFF_XOT  = 91103232;     // xoT fp16 (16,1024,512)      16,777,216
// end: 107,880,448  (round-1 proved ws >= 124,133,376)

DEV f32x16 zero16() {
  f32x16 z;
  #pragma unroll
  for (int i = 0; i < 16; ++i) z[i] = 0.f;
  return z;
}

DEV unsigned pk2(float a, float b) {
  auto h = __builtin_amdgcn_cvt_pkrtz(a, b);   // v_cvt_pkrtz_f16_f32
  union { decltype(h) x; unsigned u; } t;
  t.x = h;
  return t.u;
}

DEV void plswap(unsigned &a, unsigned &b) {
  // v_permlane32_swap_b32: both outputs usable (guide T12 recipe/arg order)
  asm("v_permlane32_swap_b32 %0, %1" : "+v"(a), "+v"(b));
}

union W4 { unsigned w[4]; f16x8 v; };

// pack 16 f32 P-values (C/D layout of one 32x32 block, k=crow(r,hi)) into two
// A-frags (k-slices 0..15 and 16..31, frag layout k = hi*8+e)
DEV void pack_block(const float p[16], f16x8 &a0, f16x8 &a1) {
  unsigned w0 = pk2(p[0], p[1]),   w1 = pk2(p[2], p[3]);
  unsigned w2 = pk2(p[4], p[5]),   w3 = pk2(p[6], p[7]);
  unsigned w4 = pk2(p[8], p[9]),   w5 = pk2(p[10], p[11]);
  unsigned w6 = pk2(p[12], p[13]), w7 = pk2(p[14], p[15]);
  plswap(w0, w2); plswap(w1, w3);
  plswap(w4, w6); plswap(w5, w7);
  W4 u; u.w[0] = w0; u.w[1] = w1; u.w[2] = w2; u.w[3] = w3; a0 = u.v;
  W4 v; v.w[0] = w4; v.w[1] = w5; v.w[2] = w6; v.w[3] = w7; a1 = v.v;
}

// ---------------------------------------------------------------------------
// prep: fp32->fp16 conversions, BN fold, zero pads
// ---------------------------------------------------------------------------
__global__ __launch_bounds__(256) void prep_kernel(
    const float* __restrict__ x, const float* __restrict__ qkv_w,
    const float* __restrict__ bn_g, const float* __restrict__ bn_b,
    const float* __restrict__ bn_m, const float* __restrict__ bn_v,
    const float* __restrict__ proj_w, const float* __restrict__ out_w,
    f16* __restrict__ x_h, f16* __restrict__ wq_h, f16* __restrict__ pw_h,
    f16* __restrict__ ow_h, float* __restrict__ bn_a, float* __restrict__ bn_sh,
    f16* __restrict__ qb, f16* __restrict__ kb, f16* __restrict__ vt,
    f16* __restrict__ opad)
{
  long tid = (long)blockIdx.x * blockDim.x + threadIdx.x;
  long gsz = (long)gridDim.x * blockDim.x;

  for (long i = tid; i < 2138112; i += gsz) {
    float4 f = ((const float4*)x)[i];
    f16x4 o = {(f16)f.x, (f16)f.y, (f16)f.z, (f16)f.w};
    ((f16x4*)x_h)[i] = o;
  }
  for (long i = tid; i < 524288; i += gsz) wq_h[i] = (f16)qkv_w[i];
  for (long i = tid; i < 1081344; i += gsz) {
    long m = i / 1056, nn = i - m * 1056;
    pw_h[i] = (nn < 1044) ? (f16)proj_w[m * 1044 + nn] : (f16)0.f;
  }
  for (long i = tid; i < 262144; i += gsz) ow_h[i] = (f16)out_w[i];
  for (long i = tid; i < 1024; i += gsz) {
    float a = bn_g[i] * rsqrtf(bn_v[i] + 1e-5f);
    bn_a[i] = a;
    bn_sh[i] = bn_b[i] - bn_m[i] * a;
  }
  // qb pad rows 1044..1151
  for (long i = tid; i < 13824; i += gsz) {
    int bh = (int)(i / 108);
    int nn = 1044 + (int)(i - (long)bh * 108);
    f16* q = qb + ((long)bh * 1152 + nn) * 32;
    for (int j = 0; j < 32; ++j) q[j] = (f16)0.f;
  }
  // kb pad rows 1044..1087
  for (long i = tid; i < 5632; i += gsz) {
    int bh = (int)(i / 44);
    int nn = 1044 + (int)(i - (long)bh * 44);
    f16* k = kb + ((long)bh * 1088 + nn) * 32;
    for (int j = 0; j < 32; ++j) k[j] = (f16)0.f;
  }
  // vt pad cols 1044..1087 for each of 128*64 rows
  for (long i = tid; i < 8192; i += gsz) {
    f16* v = vt + i * 1088 + 1044;
    for (int j = 0; j < 44; ++j) v[j] = (f16)0.f;
  }
  // opad pad cols 1044..1055
  for (long i = tid; i < 8192; i += gsz) {
    f16* o = opad + i * 1056 + 1044;
    for (int j = 0; j < 12; ++j) o[j] = (f16)0.f;
  }
}

// ---------------------------------------------------------------------------
// shared 128x128xK NT-GEMM core (unchanged from round 1)
// ---------------------------------------------------------------------------
DEV void gemm_core(const f16* __restrict__ A, const f16* __restrict__ B,
                   int lda, int ldb, int kIters, int rowClamp,
                   f16* As, f16* Bs, f32x4 acc[4][4])
{
  const int t = threadIdx.x;
  const int wave = t >> 6, lane = t & 63;
  const int wr = wave >> 1, wc = wave & 1;
  const int r0 = t >> 2, seg = t & 3;
  const int fr = lane & 15, fg = lane >> 4;
  const int ra0 = imin(r0, rowClamp);
  const int ra1 = imin(r0 + 64, rowClamp);
  for (int kt = 0; kt < kIters; ++kt) {
    const int kb = kt * 32 + seg * 8;
    f16x8 a0 = *(const f16x8*)(A + (long)ra0 * lda + kb);
    f16x8 a1 = *(const f16x8*)(A + (long)ra1 * lda + kb);
    f16x8 b0 = *(const f16x8*)(B + (long)r0 * ldb + kb);
    f16x8 b1 = *(const f16x8*)(B + (long)(r0 + 64) * ldb + kb);
    __syncthreads();
    *(f16x8*)(As + r0 * 40 + seg * 8) = a0;
    *(f16x8*)(As + (r0 + 64) * 40 + seg * 8) = a1;
    *(f16x8*)(Bs + r0 * 40 + seg * 8) = b0;
    *(f16x8*)(Bs + (r0 + 64) * 40 + seg * 8) = b1;
    __syncthreads();
    f16x8 af[4], bf[4];
    #pragma unroll
    for (int m = 0; m < 4; ++m)
      af[m] = *(const f16x8*)(As + (wr * 64 + m * 16 + fr) * 40 + fg * 8);
    #pragma unroll
    for (int n = 0; n < 4; ++n)
      bf[n] = *(const f16x8*)(Bs + (wc * 64 + n * 16 + fr) * 40 + fg * 8);
    #pragma unroll
    for (int m = 0; m < 4; ++m)
      #pragma unroll
      for (int n = 0; n < 4; ++n)
        acc[m][n] = __builtin_amdgcn_mfma_f32_16x16x32_f16(af[m], bf[n], acc[m][n], 0, 0, 0);
  }
}

// ---------------------------------------------------------------------------
// QKV GEMM + BN epilogue -> q (pre-scaled, 1152 rows), k, v^T
// grid (8, 131)
// ---------------------------------------------------------------------------
__global__ __launch_bounds__(256) void qkv_gemm(
    const f16* __restrict__ x_h, const f16* __restrict__ wq,
    const float* __restrict__ bn_a, const float* __restrict__ bn_sh,
    f16* __restrict__ qb, f16* __restrict__ kb, f16* __restrict__ vt)
{
  __shared__ f16 As[128 * 40];
  __shared__ f16 Bs[128 * 40];
  const int row0 = blockIdx.y * 128, col0 = blockIdx.x * 128;
  f32x4 acc[4][4];
  #pragma unroll
  for (int m = 0; m < 4; ++m)
    #pragma unroll
    for (int n = 0; n < 4; ++n) acc[m][n] = (f32x4){0.f, 0.f, 0.f, 0.f};
  gemm_core(x_h + (long)row0 * 512, wq + (long)col0 * 512, 512, 512, 16,
            16703 - row0, As, Bs, acc);
  const int lane = threadIdx.x & 63, wave = threadIdx.x >> 6;
  const int wr = wave >> 1, wc = wave & 1, fr = lane & 15, fg = lane >> 4;
  float ba[4], bsh[4];
  int chs[4];
  #pragma unroll
  for (int n = 0; n < 4; ++n) {
    int ch = col0 + wc * 64 + n * 16 + fr;
    chs[n] = ch; ba[n] = bn_a[ch]; bsh[n] = bn_sh[ch];
  }
  #pragma unroll
  for (int m = 0; m < 4; ++m) {
    #pragma unroll
    for (int rr = 0; rr < 4; ++rr) {
      int row = row0 + wr * 64 + m * 16 + fg * 4 + rr;
      if (row < 16704) {
        int bi = row / 1044;
        int ni = row - bi * 1044;
        #pragma unroll
        for (int n = 0; n < 4; ++n) {
          float val = acc[m][n][rr] * ba[n] + bsh[n];
          int ch = chs[n];
          int hh = ch >> 7, r = ch & 127;
          long bh = (long)(bi * 8 + hh);
          if (r < 32)      qb[(bh * 1152 + ni) * 32 + r] = (f16)(val * QSCALE);
          else if (r < 64) kb[(bh * 1088 + ni) * 32 + (r - 32)] = (f16)val;
          else             vt[(bh * 64 + (r - 64)) * 1088 + ni] = (f16)val;
        }
      }
    }
  }
}

// ---------------------------------------------------------------------------
// depthwise conv branch, reads v^T.  channel c=h*64+ci, pixel p=s1*32+s2
// maps to v[n=ci*16+(s1>>1)][d=(s1&1)*32+s2].  writes vcT[b][p][c] fp16.
// grid (32, 16)
// ---------------------------------------------------------------------------
__global__ __launch_bounds__(256) void conv_kernel(
    const f16* __restrict__ vt, const float* __restrict__ conv_w,
    const float* __restrict__ conv_b, f16* __restrict__ vcT)
{
  __shared__ f16 img[16][34][36];
  const int b = blockIdx.y, g = blockIdx.x;
  const int c0 = g * 16, h = c0 >> 6, ci0 = c0 & 63;
  const int t = threadIdx.x;
  for (int i = t; i < 16 * 34 * 36; i += 256) ((f16*)img)[i] = (f16)0.f;
  __syncthreads();
  const int d = t >> 2, seg = t & 3;
  const f16* src = vt + ((long)(b * 8 + h) * 64 + d) * 1088 + ci0 * 16 + seg * 64;
  const int dhib = d >> 5;
  const int s2 = d & 31;
  #pragma unroll
  for (int j = 0; j < 8; ++j) {
    f16x8 vv = *(const f16x8*)(src + j * 8);
    #pragma unroll
    for (int e = 0; e < 8; ++e) {
      int local = seg * 64 + j * 8 + e;
      int cl = local >> 4, rr = local & 15;
      float xv = (float)vv[e];
      float hs = xv * fminf(fmaxf(xv + 3.f, 0.f), 6.f) * (1.f / 6.f);
      img[cl][1 + rr * 2 + dhib][1 + s2] = (f16)hs;
    }
  }
  __syncthreads();
  const int cl = t & 15, pg = t >> 4;
  const int c = c0 + cl;
  float w[9];
  #pragma unroll
  for (int i = 0; i < 9; ++i) w[i] = conv_w[c * 9 + i];
  const float bias = conv_b[c];
  for (int i = 0; i < 64; ++i) {
    int p = pg + i * 16;
    int s1 = p >> 5, ss2 = p & 31;
    float a = bias;
    #pragma unroll
    for (int di = 0; di < 3; ++di)
      #pragma unroll
      for (int dj = 0; dj < 3; ++dj)
        a += w[di * 3 + dj] * (float)img[cl][s1 + di][ss2 + dj];
    vcT[((long)b * 1024 + p) * 512 + c] = (f16)a;
  }
}

// ---------------------------------------------------------------------------
// fused attention, 32x32 swapped-QK, no-max streaming softmax, barrier-free.
// 4 waves x 32 q per block; 17 k-tiles of 64.  grid (9, 128), XCD-grouped.
// ---------------------------------------------------------------------------
__global__ __launch_bounds__(256) void attn_kernel(
    const f16* __restrict__ qb, const f16* __restrict__ kb,
    const f16* __restrict__ vt, f16* __restrict__ opad)
{
  __shared__ float l_sh[4][32];
  // XCD grouping: 1152 blocks = 144 per XCD; each XCD owns 16 bh
  const int id = blockIdx.x + blockIdx.y * 9;
  const int xcd = id & 7, sl = id >> 3;
  const int bh = xcd * 16 + sl / 9, qblk = sl % 9;
  const int b = bh >> 3, h = bh & 7;
  const int wave = threadIdx.x >> 6, lane = threadIdx.x & 63;
  const int lq = lane & 31, hi = lane >> 5;
  const int q0 = qblk * 128 + wave * 32;

  const f16* qb_ = qb + (long)bh * 1152 * 32;
  const f16* kb_ = kb + (long)bh * 1088 * 32;
  const f16* vt_ = vt + (long)bh * 64 * 1088;

  const f16x8 qf0 = *(const f16x8*)(qb_ + (long)(q0 + lq) * 32 + hi * 8);
  const f16x8 qf1 = *(const f16x8*)(qb_ + (long)(q0 + lq) * 32 + 16 + hi * 8);

  f32x16 o0 = zero16(), o1 = zero16();
  float lsum = 0.f;

  auto tile = [&](int kt, bool last) {
    // V^T B-frags straight from global (L2-resident)
    f16x8 vf[2][4];
    #pragma unroll
    for (int nd = 0; nd < 2; ++nd)
      #pragma unroll
      for (int ks = 0; ks < 4; ++ks)
        vf[nd][ks] = *(const f16x8*)(vt_ + (long)(nd * 32 + lq) * 1088 +
                                     kt * 64 + ks * 16 + hi * 8);
    // K A-frags
    f16x8 kf[2][2];
    #pragma unroll
    for (int blk = 0; blk < 2; ++blk)
      #pragma unroll
      for (int ss = 0; ss < 2; ++ss)
        kf[blk][ss] = *(const f16x8*)(kb_ + (long)(kt * 64 + blk * 32 + lq) * 32 +
                                      ss * 16 + hi * 8);
    // S^T = K @ Q^T : col = q (lane&31), row-regs = k (crow)
    f32x16 s0 = zero16(), s1 = zero16();
    s0 = __builtin_amdgcn_mfma_f32_32x32x16_f16(kf[0][0], qf0, s0, 0, 0, 0);
    s0 = __builtin_amdgcn_mfma_f32_32x32x16_f16(kf[0][1], qf1, s0, 0, 0, 0);
    s1 = __builtin_amdgcn_mfma_f32_32x32x16_f16(kf[1][0], qf0, s1, 0, 0, 0);
    s1 = __builtin_amdgcn_mfma_f32_32x32x16_f16(kf[1][1], qf1, s1, 0, 0, 0);
    float p0[16], p1[16];
    #pragma unroll
    for (int r = 0; r < 16; ++r) { p0[r] = EXP2(s0[r]); p1[r] = EXP2(s1[r]); }
    if (last) {
      // k-tile 16: valid k = 1024..1043 -> crow < 20 in block0, none in block1
      #pragma unroll
      for (int r = 0; r < 16; ++r) {
        int cr = (r & 3) + 8 * (r >> 2) + 4 * hi;
        p0[r] = (cr < 20) ? p0[r] : 0.f;
        p1[r] = 0.f;
      }
    }
    // column sum (per-lane partial; cross-hi combined after the loop)
    float t8[8];
    #pragma unroll
    for (int r = 0; r < 8; ++r) t8[r] = (p0[r] + p0[r + 8]) + (p1[r] + p1[r + 8]);
    lsum += ((t8[0] + t8[1]) + (t8[2] + t8[3])) + ((t8[4] + t8[5]) + (t8[6] + t8[7]));
    // pack P into PV A-frags (cvt_pk + permlane32_swap)
    f16x8 pa[4];
    pack_block(p0, pa[0], pa[1]);
    pack_block(p1, pa[2], pa[3]);
    #pragma unroll
    for (int ks = 0; ks < 4; ++ks) {
      o0 = __builtin_amdgcn_mfma_f32_32x32x16_f16(pa[ks], vf[0][ks], o0, 0, 0, 0);
      o1 = __builtin_amdgcn_mfma_f32_32x32x16_f16(pa[ks], vf[1][ks], o1, 0, 0, 0);
    }
  };

  #pragma unroll 1
  for (int kt = 0; kt < 16; ++kt) tile(kt, false);
  tile(16, true);

  lsum += __shfl_xor(lsum, 32);
  l_sh[wave][lq] = lsum;
  __syncthreads();
  float invl[16];
  #pragma unroll
  for (int r = 0; r < 16; ++r) {
    int cr = (r & 3) + 8 * (r >> 2) + 4 * hi;
    invl[r] = __builtin_amdgcn_rcpf(l_sh[wave][cr]);
  }
  // scatter O through torch raw reshape: flat = q*512 + h*64 + d
  #pragma unroll
  for (int nd = 0; nd < 2; ++nd) {
    #pragma unroll
    for (int r = 0; r < 16; ++r) {
      int cr = (r & 3) + 8 * (r >> 2) + 4 * hi;
      int q = q0 + cr;
      if (q < 1044) {
        float val = (nd ? o1[r] : o0[r]) * invl[r];
        unsigned flat = (unsigned)q * 512u + (unsigned)h * 64u + (unsigned)(nd * 32 + lq);
        unsigned c = flat / 1044u;
        unsigned np = flat - c * 1044u;
        opad[((long)b * 512 + c) * 1056 + np] = (f16)val;
      }
    }
  }
}

// ---------------------------------------------------------------------------
// proj GEMM: xoT[b][m][c] = sum_n pw[m,n]*o[b,c,n] + proj_b[m] + vcT[b][m][c]
// grid (4, 8, 16)
// ---------------------------------------------------------------------------
__global__ __launch_bounds__(256) void proj_gemm(
    const f16* __restrict__ pw, const f16* __restrict__ opad,
    const float* __restrict__ proj_b, const f16* __restrict__ vcT,
    f16* __restrict__ xoT)
{
  __shared__ f16 As[128 * 40];
  __shared__ f16 Bs[128 * 40];
  const int b = blockIdx.z;
  const int row0 = blockIdx.y * 128;  // m (image pixel)
  const int col0 = blockIdx.x * 128;  // c (channel)
  f32x4 acc[4][4];
  #pragma unroll
  for (int m = 0; m < 4; ++m)
    #pragma unroll
    for (int n = 0; n < 4; ++n) acc[m][n] = (f32x4){0.f, 0.f, 0.f, 0.f};
  gemm_core(pw + (long)row0 * 1056, opad + ((long)b * 512 + col0) * 1056,
            1056, 1056, 33, 1 << 30, As, Bs, acc);
  const int lane = threadIdx.x & 63, wave = threadIdx.x >> 6;
  const int wr = wave >> 1, wc = wave & 1, fr = lane & 15, fg = lane >> 4;
  #pragma unroll
  for (int m = 0; m < 4; ++m) {
    #pragma unroll
    for (int rr = 0; rr < 4; ++rr) {
      int mi = row0 + wr * 64 + m * 16 + fg * 4 + rr;
      float pb = proj_b[mi];
      #pragma unroll
      for (int n = 0; n < 4; ++n) {
        int c = col0 + wc * 64 + n * 16 + fr;
        long idx = ((long)b * 1024 + mi) * 512 + c;
        xoT[idx] = (f16)(acc[m][n][rr] + pb + (float)vcT[idx]);
      }
    }
  }
}

// ---------------------------------------------------------------------------
// out GEMM: out[b,m,co] = sum_c xoT[b,m,c]*ow[co,c] + out_b[co]  (fp32 out)
// grid (4, 8, 16)
// ---------------------------------------------------------------------------
__global__ __launch_bounds__(256) void out_gemm(
    const f16* __restrict__ xoT, const f16* __restrict__ ow,
    const float* __restrict__ out_b, float* __restrict__ out)
{
  __shared__ f16 As[128 * 40];
  __shared__ f16 Bs[128 * 40];
  const int b = blockIdx.z;
  const int row0 = blockIdx.y * 128;
  const int col0 = blockIdx.x * 128;
  f32x4 acc[4][4];
  #pragma unroll
  for (int m = 0; m < 4; ++m)
    #pragma unroll
    for (int n = 0; n < 4; ++n) acc[m][n] = (f32x4){0.f, 0.f, 0.f, 0.f};
  gemm_core(xoT + ((long)b * 1024 + row0) * 512, ow + (long)col0 * 512,
            512, 512, 16, 1 << 30, As, Bs, acc);
  const int lane = threadIdx.x & 63, wave = threadIdx.x >> 6;
  const int wr = wave >> 1, wc = wave & 1, fr = lane & 15, fg = lane >> 4;
  float ob[4];
  #pragma unroll
  for (int n = 0; n < 4; ++n) ob[n] = out_b[col0 + wc * 64 + n * 16 + fr];
  #pragma unroll
  for (int m = 0; m < 4; ++m) {
    #pragma unroll
    for (int rr = 0; rr < 4; ++rr) {
      int mi = row0 + wr * 64 + m * 16 + fg * 4 + rr;
      #pragma unroll
      for (int n = 0; n < 4; ++n) {
        int co = col0 + wc * 64 + n * 16 + fr;
        out[((long)b * 1024 + mi) * 512 + co] = acc[m][n][rr] + ob[n];
      }
    }
  }
}

// ---------------------------------------------------------------------------
extern "C" void kernel_launch(void* const* d_in, const int* in_sizes, int n_in,
                              void* d_out, int out_size, void* d_ws, size_t ws_size,
                              hipStream_t stream) {
  const float* x      = (const float*)d_in[0];
  const float* qkv_w  = (const float*)d_in[1];
  const float* bn_g   = (const float*)d_in[2];
  const float* bn_b   = (const float*)d_in[3];
  const float* bn_m   = (const float*)d_in[4];
  const float* bn_v   = (const float*)d_in[5];
  const float* conv_w = (const float*)d_in[6];
  const float* conv_b = (const float*)d_in[7];
  const float* proj_w = (const float*)d_in[8];
  const float* proj_b = (const float*)d_in[9];
  const float* out_w  = (const float*)d_in[10];
  const float* out_b  = (const float*)d_in[11];
  float* out = (float*)d_out;

  char* ws = (char*)d_ws;
  f16*   x_h   = (f16*)(ws + OFF_XH);
  f16*   wq_h  = (f16*)(ws + OFF_WQ);
  f16*   pw_h  = (f16*)(ws + OFF_PW);
  f16*   ow_h  = (f16*)(ws + OFF_OW);
  float* bn_a  = (float*)(ws + OFF_BNA);
  float* bn_sh = (float*)(ws + OFF_BNB);
  f16*   qb    = (f16*)(ws + OFF_QB);
  f16*   kb    = (f16*)(ws + OFF_KB);
  f16*   vt    = (f16*)(ws + OFF_VT);
  f16*   opad  = (f16*)(ws + OFF_OPAD);
  f16*   vcT   = (f16*)(ws + OFF_VCT);
  f16*   xoT   = (f16*)(ws + OFF_XOT);

  prep_kernel<<<1024, 256, 0, stream>>>(x, qkv_w, bn_g, bn_b, bn_m, bn_v,
                                        proj_w, out_w, x_h, wq_h, pw_h, ow_h,
                                        bn_a, bn_sh, qb, kb, vt, opad);
  qkv_gemm<<<dim3(8, 131), 256, 0, stream>>>(x_h, wq_h, bn_a, bn_sh, qb, kb, vt);
  conv_kernel<<<dim3(32, 16), 256, 0, stream>>>(vt, conv_w, conv_b, vcT);
  attn_kernel<<<dim3(9, 128), 256, 0, stream>>>(qb, kb, vt, opad);
  proj_gemm<<<dim3(4, 8, 16), 256, 0, stream>>>(pw_h, opad, proj_b, vcT, xoT);
  out_gemm<<<dim3(4, 8, 16), 256, 0, stream>>>(xoT, ow_h, out_b, out);
}

// Round 3
// 198.368 us; speedup vs baseline: 1.5563x; 1.2024x over previous
//
#include <hip/hip_runtime.h>
#include <hip/hip_fp16.h>

typedef _Float16 f16;
typedef _Float16 f16x8 __attribute__((ext_vector_type(8)));
typedef _Float16 f16x4 __attribute__((ext_vector_type(4)));
typedef float    f32x4 __attribute__((ext_vector_type(4)));
typedef float    f32x16 __attribute__((ext_vector_type(16)));

#define DEV __device__ __forceinline__

DEV int imin(int a, int b) { return a < b ? a : b; }

#if defined(__has_builtin)
#  if __has_builtin(__builtin_amdgcn_exp2f)
#    define EXP2(x) __builtin_amdgcn_exp2f(x)
#  else
#    define EXP2(x) __expf((x) * 0.6931471805599453f)
#  endif
#else
#  define EXP2(x) __expf((x) * 0.6931471805599453f)
#endif

// q pre-scale: (1/sqrt(32)) * log2(e) so softmax is p = 2^s
#define QSCALE (0.17677669529663687f * 1.4426950408889634f)

// ---------------------------------------------------------------------------
// Problem constants: B=16, N=1044, DIM=512, H=8, KD=32, D=64
// q padded to 1152 rows, k/v to 1088, o cols to 1056
// ---------------------------------------------------------------------------

// workspace offsets (bytes)
constexpr size_t OFF_XH   = 0;            // x fp16 (16704,512)          17,104,896
constexpr size_t OFF_WQ   = 17104896;     // qkv_w fp16 (1024,512)        1,048,576
constexpr size_t OFF_PW   = 18153472;     // proj_w fp16 (1024,1056)      2,162,688
constexpr size_t OFF_OW   = 20316160;     // out_w fp16 (512,512)           524,288
constexpr size_t OFF_BNA  = 20840448;     // bn scale fp32 (1024)
constexpr size_t OFF_BNB  = 20844544;     // bn shift fp32 (1024)
constexpr size_t OFF_QB   = 20848640;     // q fp16 (128,1152,32)         9,437,184
constexpr size_t OFF_KB   = 30285824;     // k fp16 (128,1088,32)         8,912,896
constexpr size_t OFF_VT   = 39198720;     // v^T fp16 (128,64,1088)      17,825,792
constexpr size_t OFF_OPAD = 57024512;     // o fp16 (16,512,1056)        17,301,504
constexpr size_t OFF_VCT  = 74326016;     // vcT fp16 (16,1024,512)      16,777,216
constexpr size_t OFF_XOT  = 91103232;     // xoT fp16 (16,1024,512)      16,777,216
// end: 107,880,448  (round-1 proved ws >= 124,133,376)

DEV f32x16 zero16() {
  f32x16 z;
  #pragma unroll
  for (int i = 0; i < 16; ++i) z[i] = 0.f;
  return z;
}

DEV unsigned pk2(float a, float b) {
  auto h = __builtin_amdgcn_cvt_pkrtz(a, b);   // v_cvt_pkrtz_f16_f32
  union { decltype(h) x; unsigned u; } t;
  t.x = h;
  return t.u;
}

DEV void plswap(unsigned &a, unsigned &b) {
  asm("v_permlane32_swap_b32 %0, %1" : "+v"(a), "+v"(b));
}

union W4 { unsigned w[4]; f16x8 v; };

// pack 16 f32 P-values (C/D layout of one 32x32 block, k=crow(r,hi)) into two
// A-frags (k-slices 0..15 and 16..31, frag layout k = hi*8+e)
DEV void pack_block(const float p[16], f16x8 &a0, f16x8 &a1) {
  unsigned w0 = pk2(p[0], p[1]),   w1 = pk2(p[2], p[3]);
  unsigned w2 = pk2(p[4], p[5]),   w3 = pk2(p[6], p[7]);
  unsigned w4 = pk2(p[8], p[9]),   w5 = pk2(p[10], p[11]);
  unsigned w6 = pk2(p[12], p[13]), w7 = pk2(p[14], p[15]);
  plswap(w0, w2); plswap(w1, w3);
  plswap(w4, w6); plswap(w5, w7);
  W4 u; u.w[0] = w0; u.w[1] = w1; u.w[2] = w2; u.w[3] = w3; a0 = u.v;
  W4 v; v.w[0] = w4; v.w[1] = w5; v.w[2] = w6; v.w[3] = w7; a1 = v.v;
}

// ---------------------------------------------------------------------------
// prep: fp32->fp16 conversions, BN fold, zero pads
// ---------------------------------------------------------------------------
__global__ __launch_bounds__(256) void prep_kernel(
    const float* __restrict__ x, const float* __restrict__ qkv_w,
    const float* __restrict__ bn_g, const float* __restrict__ bn_b,
    const float* __restrict__ bn_m, const float* __restrict__ bn_v,
    const float* __restrict__ proj_w, const float* __restrict__ out_w,
    f16* __restrict__ x_h, f16* __restrict__ wq_h, f16* __restrict__ pw_h,
    f16* __restrict__ ow_h, float* __restrict__ bn_a, float* __restrict__ bn_sh,
    f16* __restrict__ qb, f16* __restrict__ kb, f16* __restrict__ vt,
    f16* __restrict__ opad)
{
  long tid = (long)blockIdx.x * blockDim.x + threadIdx.x;
  long gsz = (long)gridDim.x * blockDim.x;

  for (long i = tid; i < 2138112; i += gsz) {
    float4 f = ((const float4*)x)[i];
    f16x4 o = {(f16)f.x, (f16)f.y, (f16)f.z, (f16)f.w};
    ((f16x4*)x_h)[i] = o;
  }
  for (long i = tid; i < 524288; i += gsz) wq_h[i] = (f16)qkv_w[i];
  for (long i = tid; i < 1081344; i += gsz) {
    long m = i / 1056, nn = i - m * 1056;
    pw_h[i] = (nn < 1044) ? (f16)proj_w[m * 1044 + nn] : (f16)0.f;
  }
  for (long i = tid; i < 262144; i += gsz) ow_h[i] = (f16)out_w[i];
  for (long i = tid; i < 1024; i += gsz) {
    float a = bn_g[i] * rsqrtf(bn_v[i] + 1e-5f);
    bn_a[i] = a;
    bn_sh[i] = bn_b[i] - bn_m[i] * a;
  }
  // qb pad rows 1044..1151
  for (long i = tid; i < 13824; i += gsz) {
    int bh = (int)(i / 108);
    int nn = 1044 + (int)(i - (long)bh * 108);
    f16* q = qb + ((long)bh * 1152 + nn) * 32;
    for (int j = 0; j < 32; ++j) q[j] = (f16)0.f;
  }
  // kb pad rows 1044..1087
  for (long i = tid; i < 5632; i += gsz) {
    int bh = (int)(i / 44);
    int nn = 1044 + (int)(i - (long)bh * 44);
    f16* k = kb + ((long)bh * 1088 + nn) * 32;
    for (int j = 0; j < 32; ++j) k[j] = (f16)0.f;
  }
  // vt pad cols 1044..1087 for each of 128*64 rows
  for (long i = tid; i < 8192; i += gsz) {
    f16* v = vt + i * 1088 + 1044;
    for (int j = 0; j < 44; ++j) v[j] = (f16)0.f;
  }
  // opad pad cols 1044..1055
  for (long i = tid; i < 8192; i += gsz) {
    f16* o = opad + i * 1056 + 1044;
    for (int j = 0; j < 12; ++j) o[j] = (f16)0.f;
  }
}

// ---------------------------------------------------------------------------
// shared 128x128xK NT-GEMM core (unchanged; 0 bank conflicts measured)
// ---------------------------------------------------------------------------
DEV void gemm_core(const f16* __restrict__ A, const f16* __restrict__ B,
                   int lda, int ldb, int kIters, int rowClamp,
                   f16* As, f16* Bs, f32x4 acc[4][4])
{
  const int t = threadIdx.x;
  const int wave = t >> 6, lane = t & 63;
  const int wr = wave >> 1, wc = wave & 1;
  const int r0 = t >> 2, seg = t & 3;
  const int fr = lane & 15, fg = lane >> 4;
  const int ra0 = imin(r0, rowClamp);
  const int ra1 = imin(r0 + 64, rowClamp);
  for (int kt = 0; kt < kIters; ++kt) {
    const int kb = kt * 32 + seg * 8;
    f16x8 a0 = *(const f16x8*)(A + (long)ra0 * lda + kb);
    f16x8 a1 = *(const f16x8*)(A + (long)ra1 * lda + kb);
    f16x8 b0 = *(const f16x8*)(B + (long)r0 * ldb + kb);
    f16x8 b1 = *(const f16x8*)(B + (long)(r0 + 64) * ldb + kb);
    __syncthreads();
    *(f16x8*)(As + r0 * 40 + seg * 8) = a0;
    *(f16x8*)(As + (r0 + 64) * 40 + seg * 8) = a1;
    *(f16x8*)(Bs + r0 * 40 + seg * 8) = b0;
    *(f16x8*)(Bs + (r0 + 64) * 40 + seg * 8) = b1;
    __syncthreads();
    f16x8 af[4], bf[4];
    #pragma unroll
    for (int m = 0; m < 4; ++m)
      af[m] = *(const f16x8*)(As + (wr * 64 + m * 16 + fr) * 40 + fg * 8);
    #pragma unroll
    for (int n = 0; n < 4; ++n)
      bf[n] = *(const f16x8*)(Bs + (wc * 64 + n * 16 + fr) * 40 + fg * 8);
    #pragma unroll
    for (int m = 0; m < 4; ++m)
      #pragma unroll
      for (int n = 0; n < 4; ++n)
        acc[m][n] = __builtin_amdgcn_mfma_f32_16x16x32_f16(af[m], bf[n], acc[m][n], 0, 0, 0);
  }
}

// ---------------------------------------------------------------------------
// QKV GEMM + BN epilogue -> q (pre-scaled, 1152 rows), k, v^T
// grid (8, 131)
// ---------------------------------------------------------------------------
__global__ __launch_bounds__(256) void qkv_gemm(
    const f16* __restrict__ x_h, const f16* __restrict__ wq,
    const float* __restrict__ bn_a, const float* __restrict__ bn_sh,
    f16* __restrict__ qb, f16* __restrict__ kb, f16* __restrict__ vt)
{
  __shared__ f16 As[128 * 40];
  __shared__ f16 Bs[128 * 40];
  const int row0 = blockIdx.y * 128, col0 = blockIdx.x * 128;
  f32x4 acc[4][4];
  #pragma unroll
  for (int m = 0; m < 4; ++m)
    #pragma unroll
    for (int n = 0; n < 4; ++n) acc[m][n] = (f32x4){0.f, 0.f, 0.f, 0.f};
  gemm_core(x_h + (long)row0 * 512, wq + (long)col0 * 512, 512, 512, 16,
            16703 - row0, As, Bs, acc);
  const int lane = threadIdx.x & 63, wave = threadIdx.x >> 6;
  const int wr = wave >> 1, wc = wave & 1, fr = lane & 15, fg = lane >> 4;
  float ba[4], bsh[4];
  int chs[4];
  #pragma unroll
  for (int n = 0; n < 4; ++n) {
    int ch = col0 + wc * 64 + n * 16 + fr;
    chs[n] = ch; ba[n] = bn_a[ch]; bsh[n] = bn_sh[ch];
  }
  #pragma unroll
  for (int m = 0; m < 4; ++m) {
    #pragma unroll
    for (int rr = 0; rr < 4; ++rr) {
      int row = row0 + wr * 64 + m * 16 + fg * 4 + rr;
      if (row < 16704) {
        int bi = row / 1044;
        int ni = row - bi * 1044;
        #pragma unroll
        for (int n = 0; n < 4; ++n) {
          float val = acc[m][n][rr] * ba[n] + bsh[n];
          int ch = chs[n];
          int hh = ch >> 7, r = ch & 127;
          long bh = (long)(bi * 8 + hh);
          if (r < 32)      qb[(bh * 1152 + ni) * 32 + r] = (f16)(val * QSCALE);
          else if (r < 64) kb[(bh * 1088 + ni) * 32 + (r - 32)] = (f16)val;
          else             vt[(bh * 64 + (r - 64)) * 1088 + ni] = (f16)val;
        }
      }
    }
  }
}

// ---------------------------------------------------------------------------
// depthwise conv branch (unchanged)
// ---------------------------------------------------------------------------
__global__ __launch_bounds__(256) void conv_kernel(
    const f16* __restrict__ vt, const float* __restrict__ conv_w,
    const float* __restrict__ conv_b, f16* __restrict__ vcT)
{
  __shared__ f16 img[16][34][36];
  const int b = blockIdx.y, g = blockIdx.x;
  const int c0 = g * 16, h = c0 >> 6, ci0 = c0 & 63;
  const int t = threadIdx.x;
  for (int i = t; i < 16 * 34 * 36; i += 256) ((f16*)img)[i] = (f16)0.f;
  __syncthreads();
  const int d = t >> 2, seg = t & 3;
  const f16* src = vt + ((long)(b * 8 + h) * 64 + d) * 1088 + ci0 * 16 + seg * 64;
  const int dhib = d >> 5;
  const int s2 = d & 31;
  #pragma unroll
  for (int j = 0; j < 8; ++j) {
    f16x8 vv = *(const f16x8*)(src + j * 8);
    #pragma unroll
    for (int e = 0; e < 8; ++e) {
      int local = seg * 64 + j * 8 + e;
      int cl = local >> 4, rr = local & 15;
      float xv = (float)vv[e];
      float hs = xv * fminf(fmaxf(xv + 3.f, 0.f), 6.f) * (1.f / 6.f);
      img[cl][1 + rr * 2 + dhib][1 + s2] = (f16)hs;
    }
  }
  __syncthreads();
  const int cl = t & 15, pg = t >> 4;
  const int c = c0 + cl;
  float w[9];
  #pragma unroll
  for (int i = 0; i < 9; ++i) w[i] = conv_w[c * 9 + i];
  const float bias = conv_b[c];
  for (int i = 0; i < 64; ++i) {
    int p = pg + i * 16;
    int s1 = p >> 5, ss2 = p & 31;
    float a = bias;
    #pragma unroll
    for (int di = 0; di < 3; ++di)
      #pragma unroll
      for (int dj = 0; dj < 3; ++dj)
        a += w[di * 3 + dj] * (float)img[cl][s1 + di][ss2 + dj];
    vcT[((long)b * 1024 + p) * 512 + c] = (f16)a;
  }
}

// ---------------------------------------------------------------------------
// fused attention v3: LDS-staged K/V tiles (fragment-major, rotation-swizzled,
// double-buffered, T14 issue-early/write-late), swapped-QK 32x32 MFMA,
// no-max streaming softmax, one barrier per tile.  grid (9,128), XCD-grouped.
// ---------------------------------------------------------------------------
__global__ __launch_bounds__(256) void attn_kernel(
    const f16* __restrict__ qb, const f16* __restrict__ kb,
    const f16* __restrict__ vt, f16* __restrict__ opad)
{
  // fragment-major tiles: kls[buf][ss2=0..3][cc=0..63][e=0..7]
  //                       vls[buf][kk8=0..7][cc=0..63][e=0..7]
  // chunk rotation cc = (row + plane) & 63 makes every 8-lane phase of a
  // b128 read/write span 8 distinct bank groups.
  __shared__ f16 kls[2][4 * 64 * 8];
  __shared__ f16 vls[2][8 * 64 * 8];
  __shared__ float l_sh[4][32];

  const int id = blockIdx.x + blockIdx.y * 9;
  const int xcd = id & 7, sl = id >> 3;
  const int bh = xcd * 16 + sl / 9, qblk = sl % 9;
  const int b = bh >> 3, h = bh & 7;
  const int t = threadIdx.x;
  const int wave = t >> 6, lane = t & 63;
  const int lq = lane & 31, hi = lane >> 5;
  const int q0 = qblk * 128 + wave * 32;

  const f16* qb_ = qb + (long)bh * 1152 * 32;
  const f16* kb_ = kb + (long)bh * 1088 * 32;
  const f16* vt_ = vt + (long)bh * 64 * 1088;

  const f16x8 qf0 = *(const f16x8*)(qb_ + (long)(q0 + lq) * 32 + hi * 8);
  const f16x8 qf1 = *(const f16x8*)(qb_ + (long)(q0 + lq) * 32 + 16 + hi * 8);

  // staging thread mapping (global coalesced)
  const int sk_k = t >> 2, sk_s = t & 3;          // K: k row, 16B chunk
  const int sv_d = t >> 3, sv_p = t & 7;          // V: d row (and +32), k-chunk
  // LDS write byte offsets (kt-invariant)
  const int wkoff  = (sk_s * 64 + ((sk_k + sk_s) & 63)) * 16;
  const int wvoff0 = (sv_p * 64 + ((sv_d + sv_p) & 63)) * 16;
  const int wvoff1 = (sv_p * 64 + ((sv_d + 32 + sv_p) & 63)) * 16;
  // frag read byte offsets (kt-invariant)
  int koff[2][2], voff[2][4];
  #pragma unroll
  for (int blk = 0; blk < 2; ++blk)
    #pragma unroll
    for (int ss = 0; ss < 2; ++ss) {
      int ss2 = 2 * ss + hi;
      koff[blk][ss] = (ss2 * 64 + ((blk * 32 + lq + ss2) & 63)) * 16;
    }
  #pragma unroll
  for (int nd = 0; nd < 2; ++nd)
    #pragma unroll
    for (int ks = 0; ks < 4; ++ks) {
      int kk8 = 2 * ks + hi;
      voff[nd][ks] = (kk8 * 64 + ((nd * 32 + lq + kk8) & 63)) * 16;
    }

  f16x8 stk, stv0, stv1;
  auto load_tile = [&](int kt) {
    stk  = *(const f16x8*)(kb_ + (long)(kt * 64 + sk_k) * 32 + sk_s * 8);
    stv0 = *(const f16x8*)(vt_ + (long)sv_d * 1088 + kt * 64 + sv_p * 8);
    stv1 = *(const f16x8*)(vt_ + (long)(sv_d + 32) * 1088 + kt * 64 + sv_p * 8);
  };
  auto write_tile = [&](int buf) {
    *(f16x8*)((char*)kls[buf] + wkoff)  = stk;
    *(f16x8*)((char*)vls[buf] + wvoff0) = stv0;
    *(f16x8*)((char*)vls[buf] + wvoff1) = stv1;
  };

  f32x16 o0 = zero16(), o1 = zero16();
  float lsum = 0.f;

  load_tile(0);
  write_tile(0);
  __syncthreads();

  int cur = 0;
  #pragma unroll 1
  for (int kt = 0; kt < 17; ++kt) {
    if (kt < 16) load_tile(kt + 1);
    const char* kcur = (const char*)kls[cur];
    const char* vcur = (const char*)vls[cur];
    // K frags from LDS
    f16x8 kf[2][2];
    #pragma unroll
    for (int blk = 0; blk < 2; ++blk)
      #pragma unroll
      for (int ss = 0; ss < 2; ++ss)
        kf[blk][ss] = *(const f16x8*)(kcur + koff[blk][ss]);
    // S^T = K @ Q^T
    f32x16 s0 = zero16(), s1 = zero16();
    s0 = __builtin_amdgcn_mfma_f32_32x32x16_f16(kf[0][0], qf0, s0, 0, 0, 0);
    s0 = __builtin_amdgcn_mfma_f32_32x32x16_f16(kf[0][1], qf1, s0, 0, 0, 0);
    s1 = __builtin_amdgcn_mfma_f32_32x32x16_f16(kf[1][0], qf0, s1, 0, 0, 0);
    s1 = __builtin_amdgcn_mfma_f32_32x32x16_f16(kf[1][1], qf1, s1, 0, 0, 0);
    float p0[16], p1[16];
    #pragma unroll
    for (int r = 0; r < 16; ++r) { p0[r] = EXP2(s0[r]); p1[r] = EXP2(s1[r]); }
    if (kt == 16) {
      #pragma unroll
      for (int r = 0; r < 16; ++r) {
        int cr = (r & 3) + 8 * (r >> 2) + 4 * hi;
        p0[r] = (cr < 20) ? p0[r] : 0.f;
        p1[r] = 0.f;
      }
    }
    float t8[8];
    #pragma unroll
    for (int r = 0; r < 8; ++r) t8[r] = (p0[r] + p0[r + 8]) + (p1[r] + p1[r + 8]);
    lsum += ((t8[0] + t8[1]) + (t8[2] + t8[3])) + ((t8[4] + t8[5]) + (t8[6] + t8[7]));
    // pack P and do PV from LDS V frags
    f16x8 pa[4];
    pack_block(p0, pa[0], pa[1]);
    pack_block(p1, pa[2], pa[3]);
    #pragma unroll
    for (int ks = 0; ks < 4; ++ks) {
      f16x8 vf0 = *(const f16x8*)(vcur + voff[0][ks]);
      f16x8 vf1 = *(const f16x8*)(vcur + voff[1][ks]);
      o0 = __builtin_amdgcn_mfma_f32_32x32x16_f16(pa[ks], vf0, o0, 0, 0, 0);
      o1 = __builtin_amdgcn_mfma_f32_32x32x16_f16(pa[ks], vf1, o1, 0, 0, 0);
    }
    if (kt < 16) write_tile(cur ^ 1);
    __syncthreads();
    cur ^= 1;
  }

  lsum += __shfl_xor(lsum, 32);
  l_sh[wave][lq] = lsum;
  __syncthreads();
  float invl[16];
  #pragma unroll
  for (int r = 0; r < 16; ++r) {
    int cr = (r & 3) + 8 * (r >> 2) + 4 * hi;
    invl[r] = __builtin_amdgcn_rcpf(l_sh[wave][cr]);
  }
  // scatter O through torch raw reshape: flat = q*512 + h*64 + d
  #pragma unroll
  for (int nd = 0; nd < 2; ++nd) {
    #pragma unroll
    for (int r = 0; r < 16; ++r) {
      int cr = (r & 3) + 8 * (r >> 2) + 4 * hi;
      int q = q0 + cr;
      if (q < 1044) {
        float val = (nd ? o1[r] : o0[r]) * invl[r];
        unsigned flat = (unsigned)q * 512u + (unsigned)h * 64u + (unsigned)(nd * 32 + lq);
        unsigned c = flat / 1044u;
        unsigned np = flat - c * 1044u;
        opad[((long)b * 512 + c) * 1056 + np] = (f16)val;
      }
    }
  }
}

// ---------------------------------------------------------------------------
// proj GEMM: xoT[b][m][c] = sum_n pw[m,n]*o[b,c,n] + proj_b[m] + vcT[b][m][c]
// grid (4, 8, 16)
// ---------------------------------------------------------------------------
__global__ __launch_bounds__(256) void proj_gemm(
    const f16* __restrict__ pw, const f16* __restrict__ opad,
    const float* __restrict__ proj_b, const f16* __restrict__ vcT,
    f16* __restrict__ xoT)
{
  __shared__ f16 As[128 * 40];
  __shared__ f16 Bs[128 * 40];
  const int b = blockIdx.z;
  const int row0 = blockIdx.y * 128;  // m (image pixel)
  const int col0 = blockIdx.x * 128;  // c (channel)
  f32x4 acc[4][4];
  #pragma unroll
  for (int m = 0; m < 4; ++m)
    #pragma unroll
    for (int n = 0; n < 4; ++n) acc[m][n] = (f32x4){0.f, 0.f, 0.f, 0.f};
  gemm_core(pw + (long)row0 * 1056, opad + ((long)b * 512 + col0) * 1056,
            1056, 1056, 33, 1 << 30, As, Bs, acc);
  const int lane = threadIdx.x & 63, wave = threadIdx.x >> 6;
  const int wr = wave >> 1, wc = wave & 1, fr = lane & 15, fg = lane >> 4;
  #pragma unroll
  for (int m = 0; m < 4; ++m) {
    #pragma unroll
    for (int rr = 0; rr < 4; ++rr) {
      int mi = row0 + wr * 64 + m * 16 + fg * 4 + rr;
      float pb = proj_b[mi];
      #pragma unroll
      for (int n = 0; n < 4; ++n) {
        int c = col0 + wc * 64 + n * 16 + fr;
        long idx = ((long)b * 1024 + mi) * 512 + c;
        xoT[idx] = (f16)(acc[m][n][rr] + pb + (float)vcT[idx]);
      }
    }
  }
}

// ---------------------------------------------------------------------------
// out GEMM: out[b,m,co] = sum_c xoT[b,m,c]*ow[co,c] + out_b[co]  (fp32 out)
// grid (4, 8, 16)
// ---------------------------------------------------------------------------
__global__ __launch_bounds__(256) void out_gemm(
    const f16* __restrict__ xoT, const f16* __restrict__ ow,
    const float* __restrict__ out_b, float* __restrict__ out)
{
  __shared__ f16 As[128 * 40];
  __shared__ f16 Bs[128 * 40];
  const int b = blockIdx.z;
  const int row0 = blockIdx.y * 128;
  const int col0 = blockIdx.x * 128;
  f32x4 acc[4][4];
  #pragma unroll
  for (int m = 0; m < 4; ++m)
    #pragma unroll
    for (int n = 0; n < 4; ++n) acc[m][n] = (f32x4){0.f, 0.f, 0.f, 0.f};
  gemm_core(xoT + ((long)b * 1024 + row0) * 512, ow + (long)col0 * 512,
            512, 512, 16, 1 << 30, As, Bs, acc);
  const int lane = threadIdx.x & 63, wave = threadIdx.x >> 6;
  const int wr = wave >> 1, wc = wave & 1, fr = lane & 15, fg = lane >> 4;
  float ob[4];
  #pragma unroll
  for (int n = 0; n < 4; ++n) ob[n] = out_b[col0 + wc * 64 + n * 16 + fr];
  #pragma unroll
  for (int m = 0; m < 4; ++m) {
    #pragma unroll
    for (int rr = 0; rr < 4; ++rr) {
      int mi = row0 + wr * 64 + m * 16 + fg * 4 + rr;
      #pragma unroll
      for (int n = 0; n < 4; ++n) {
        int co = col0 + wc * 64 + n * 16 + fr;
        out[((long)b * 1024 + mi) * 512 + co] = acc[m][n][rr] + ob[n];
      }
    }
  }
}

// ---------------------------------------------------------------------------
extern "C" void kernel_launch(void* const* d_in, const int* in_sizes, int n_in,
                              void* d_out, int out_size, void* d_ws, size_t ws_size,
                              hipStream_t stream) {
  const float* x      = (const float*)d_in[0];
  const float* qkv_w  = (const float*)d_in[1];
  const float* bn_g   = (const float*)d_in[2];
  const float* bn_b   = (const float*)d_in[3];
  const float* bn_m   = (const float*)d_in[4];
  const float* bn_v   = (const float*)d_in[5];
  const float* conv_w = (const float*)d_in[6];
  const float* conv_b = (const float*)d_in[7];
  const float* proj_w = (const float*)d_in[8];
  const float* proj_b = (const float*)d_in[9];
  const float* out_w  = (const float*)d_in[10];
  const float* out_b  = (const float*)d_in[11];
  float* out = (float*)d_out;

  char* ws = (char*)d_ws;
  f16*   x_h   = (f16*)(ws + OFF_XH);
  f16*   wq_h  = (f16*)(ws + OFF_WQ);
  f16*   pw_h  = (f16*)(ws + OFF_PW);
  f16*   ow_h  = (f16*)(ws + OFF_OW);
  float* bn_a  = (float*)(ws + OFF_BNA);
  float* bn_sh = (float*)(ws + OFF_BNB);
  f16*   qb    = (f16*)(ws + OFF_QB);
  f16*   kb    = (f16*)(ws + OFF_KB);
  f16*   vt    = (f16*)(ws + OFF_VT);
  f16*   opad  = (f16*)(ws + OFF_OPAD);
  f16*   vcT   = (f16*)(ws + OFF_VCT);
  f16*   xoT   = (f16*)(ws + OFF_XOT);

  prep_kernel<<<1024, 256, 0, stream>>>(x, qkv_w, bn_g, bn_b, bn_m, bn_v,
                                        proj_w, out_w, x_h, wq_h, pw_h, ow_h,
                                        bn_a, bn_sh, qb, kb, vt, opad);
  qkv_gemm<<<dim3(8, 131), 256, 0, stream>>>(x_h, wq_h, bn_a, bn_sh, qb, kb, vt);
  conv_kernel<<<dim3(32, 16), 256, 0, stream>>>(vt, conv_w, conv_b, vcT);
  attn_kernel<<<dim3(9, 128), 256, 0, stream>>>(qb, kb, vt, opad);
  proj_gemm<<<dim3(4, 8, 16), 256, 0, stream>>>(pw_h, opad, proj_b, vcT, xoT);
  out_gemm<<<dim3(4, 8, 16), 256, 0, stream>>>(xoT, ow_h, out_b, out);
}

// Round 6
// 193.034 us; speedup vs baseline: 1.5993x; 1.0276x over previous
//
#include <hip/hip_runtime.h>
#include <hip/hip_fp16.h>

typedef _Float16 f16;
typedef _Float16 f16x8 __attribute__((ext_vector_type(8)));
typedef _Float16 f16x4 __attribute__((ext_vector_type(4)));
typedef float    f32x4 __attribute__((ext_vector_type(4)));
typedef float    f32x16 __attribute__((ext_vector_type(16)));

#define DEV __device__ __forceinline__

DEV int imin(int a, int b) { return a < b ? a : b; }

#if defined(__has_builtin)
#  if __has_builtin(__builtin_amdgcn_exp2f)
#    define EXP2(x) __builtin_amdgcn_exp2f(x)
#  else
#    define EXP2(x) __expf((x) * 0.6931471805599453f)
#  endif
#else
#  define EXP2(x) __expf((x) * 0.6931471805599453f)
#endif

// q pre-scale: (1/sqrt(32)) * log2(e) so softmax is p = 2^s
#define QSCALE (0.17677669529663687f * 1.4426950408889634f)

// ---------------------------------------------------------------------------
// Problem constants: B=16, N=1044, DIM=512, H=8, KD=32, D=64
// q padded to 1152 rows, k/v to 1088, o cols to 1056   (round-3 layout)
// ---------------------------------------------------------------------------

// workspace offsets (bytes) — round-3 proven layout
constexpr size_t OFF_XH   = 0;            // x fp16 (16704,512)          17,104,896
constexpr size_t OFF_WQ   = 17104896;     // qkv_w fp16 (1024,512)        1,048,576
constexpr size_t OFF_PW   = 18153472;     // proj_w fp16 (1024,1056)      2,162,688
constexpr size_t OFF_OW   = 20316160;     // out_w fp16 (512,512)           524,288
constexpr size_t OFF_BNA  = 20840448;     // bn scale fp32 (1024)
constexpr size_t OFF_BNB  = 20844544;     // bn shift fp32 (1024)
constexpr size_t OFF_QB   = 20848640;     // q fp16 (128,1152,32)         9,437,184
constexpr size_t OFF_KB   = 30285824;     // k fp16 (128,1088,32)         8,912,896
constexpr size_t OFF_VT   = 39198720;     // v^T fp16 (128,64,1088)      17,825,792
constexpr size_t OFF_OPAD = 57024512;     // o fp16 (16,512,1056)        17,301,504
constexpr size_t OFF_VCT  = 74326016;     // vcT fp16 (16,1024,512)      16,777,216
constexpr size_t OFF_XOT  = 91103232;     // xoT fp16 (16,1024,512)      16,777,216

DEV f32x16 zero16() {
  f32x16 z;
  #pragma unroll
  for (int i = 0; i < 16; ++i) z[i] = 0.f;
  return z;
}

DEV unsigned pk2(float a, float b) {
  auto h = __builtin_amdgcn_cvt_pkrtz(a, b);
  union { decltype(h) x; unsigned u; } t;
  t.x = h;
  return t.u;
}

DEV void plswap(unsigned &a, unsigned &b) {
  asm("v_permlane32_swap_b32 %0, %1" : "+v"(a), "+v"(b));
}

union W4 { unsigned w[4]; f16x8 v; };

DEV void pack_block(const float p[16], f16x8 &a0, f16x8 &a1) {
  unsigned w0 = pk2(p[0], p[1]),   w1 = pk2(p[2], p[3]);
  unsigned w2 = pk2(p[4], p[5]),   w3 = pk2(p[6], p[7]);
  unsigned w4 = pk2(p[8], p[9]),   w5 = pk2(p[10], p[11]);
  unsigned w6 = pk2(p[12], p[13]), w7 = pk2(p[14], p[15]);
  plswap(w0, w2); plswap(w1, w3);
  plswap(w4, w6); plswap(w5, w7);
  W4 u; u.w[0] = w0; u.w[1] = w1; u.w[2] = w2; u.w[3] = w3; a0 = u.v;
  W4 v; v.w[0] = w4; v.w[1] = w5; v.w[2] = w6; v.w[3] = w7; a1 = v.v;
}

// ---------------------------------------------------------------------------
// prep: fp32->fp16 conversions, BN fold, zero pads   (round-3 verbatim)
// ---------------------------------------------------------------------------
__global__ __launch_bounds__(256) void prep_kernel(
    const float* __restrict__ x, const float* __restrict__ qkv_w,
    const float* __restrict__ bn_g, const float* __restrict__ bn_b,
    const float* __restrict__ bn_m, const float* __restrict__ bn_v,
    const float* __restrict__ proj_w, const float* __restrict__ out_w,
    f16* __restrict__ x_h, f16* __restrict__ wq_h, f16* __restrict__ pw_h,
    f16* __restrict__ ow_h, float* __restrict__ bn_a, float* __restrict__ bn_sh,
    f16* __restrict__ qb, f16* __restrict__ kb, f16* __restrict__ vt,
    f16* __restrict__ opad)
{
  long tid = (long)blockIdx.x * blockDim.x + threadIdx.x;
  long gsz = (long)gridDim.x * blockDim.x;

  for (long i = tid; i < 2138112; i += gsz) {
    float4 f = ((const float4*)x)[i];
    f16x4 o = {(f16)f.x, (f16)f.y, (f16)f.z, (f16)f.w};
    ((f16x4*)x_h)[i] = o;
  }
  for (long i = tid; i < 524288; i += gsz) wq_h[i] = (f16)qkv_w[i];
  for (long i = tid; i < 1081344; i += gsz) {
    long m = i / 1056, nn = i - m * 1056;
    pw_h[i] = (nn < 1044) ? (f16)proj_w[m * 1044 + nn] : (f16)0.f;
  }
  for (long i = tid; i < 262144; i += gsz) ow_h[i] = (f16)out_w[i];
  for (long i = tid; i < 1024; i += gsz) {
    float a = bn_g[i] * rsqrtf(bn_v[i] + 1e-5f);
    bn_a[i] = a;
    bn_sh[i] = bn_b[i] - bn_m[i] * a;
  }
  // qb pad rows 1044..1151
  for (long i = tid; i < 13824; i += gsz) {
    int bh = (int)(i / 108);
    int nn = 1044 + (int)(i - (long)bh * 108);
    f16* q = qb + ((long)bh * 1152 + nn) * 32;
    for (int j = 0; j < 32; ++j) q[j] = (f16)0.f;
  }
  // kb pad rows 1044..1087
  for (long i = tid; i < 5632; i += gsz) {
    int bh = (int)(i / 44);
    int nn = 1044 + (int)(i - (long)bh * 44);
    f16* k = kb + ((long)bh * 1088 + nn) * 32;
    for (int j = 0; j < 32; ++j) k[j] = (f16)0.f;
  }
  // vt pad cols 1044..1087
  for (long i = tid; i < 8192; i += gsz) {
    f16* v = vt + i * 1088 + 1044;
    for (int j = 0; j < 44; ++j) v[j] = (f16)0.f;
  }
  // opad pad cols 1044..1055
  for (long i = tid; i < 8192; i += gsz) {
    f16* o = opad + i * 1056 + 1044;
    for (int j = 0; j < 12; ++j) o[j] = (f16)0.f;
  }
}

// ---------------------------------------------------------------------------
// shared 128x128xK NT-GEMM core (round-3 verbatim; 0 bank conflicts measured)
// ---------------------------------------------------------------------------
DEV void gemm_core(const f16* __restrict__ A, const f16* __restrict__ B,
                   int lda, int ldb, int kIters, int rowClamp,
                   f16* As, f16* Bs, f32x4 acc[4][4])
{
  const int t = threadIdx.x;
  const int wave = t >> 6, lane = t & 63;
  const int wr = wave >> 1, wc = wave & 1;
  const int r0 = t >> 2, seg = t & 3;
  const int fr = lane & 15, fg = lane >> 4;
  const int ra0 = imin(r0, rowClamp);
  const int ra1 = imin(r0 + 64, rowClamp);
  for (int kt = 0; kt < kIters; ++kt) {
    const int kb = kt * 32 + seg * 8;
    f16x8 a0 = *(const f16x8*)(A + (long)ra0 * lda + kb);
    f16x8 a1 = *(const f16x8*)(A + (long)ra1 * lda + kb);
    f16x8 b0 = *(const f16x8*)(B + (long)r0 * ldb + kb);
    f16x8 b1 = *(const f16x8*)(B + (long)(r0 + 64) * ldb + kb);
    __syncthreads();
    *(f16x8*)(As + r0 * 40 + seg * 8) = a0;
    *(f16x8*)(As + (r0 + 64) * 40 + seg * 8) = a1;
    *(f16x8*)(Bs + r0 * 40 + seg * 8) = b0;
    *(f16x8*)(Bs + (r0 + 64) * 40 + seg * 8) = b1;
    __syncthreads();
    f16x8 af[4], bf[4];
    #pragma unroll
    for (int m = 0; m < 4; ++m)
      af[m] = *(const f16x8*)(As + (wr * 64 + m * 16 + fr) * 40 + fg * 8);
    #pragma unroll
    for (int n = 0; n < 4; ++n)
      bf[n] = *(const f16x8*)(Bs + (wc * 64 + n * 16 + fr) * 40 + fg * 8);
    #pragma unroll
    for (int m = 0; m < 4; ++m)
      #pragma unroll
      for (int n = 0; n < 4; ++n)
        acc[m][n] = __builtin_amdgcn_mfma_f32_16x16x32_f16(af[m], bf[n], acc[m][n], 0, 0, 0);
  }
}

// ---------------------------------------------------------------------------
// QKV GEMM + BN epilogue -> q (pre-scaled), k, v^T.  grid dim3(8,131);
// NEW: XCD-locality block remap (only change vs round 3).
// ---------------------------------------------------------------------------
__global__ __launch_bounds__(256) void qkv_gemm(
    const f16* __restrict__ x_h, const f16* __restrict__ wq,
    const float* __restrict__ bn_a, const float* __restrict__ bn_sh,
    f16* __restrict__ qb, f16* __restrict__ kb, f16* __restrict__ vt)
{
  __shared__ f16 As[128 * 40];
  __shared__ f16 Bs[128 * 40];
  // dispatch-order id; each XCD (id&7) owns a contiguous band of row-blocks
  const int id = blockIdx.x + blockIdx.y * 8;          // [0,1048)
  const int lin = (id & 7) * 131 + (id >> 3);          // bijective [0,1048)
  const int row0 = (lin >> 3) * 128, col0 = (lin & 7) * 128;
  f32x4 acc[4][4];
  #pragma unroll
  for (int m = 0; m < 4; ++m)
    #pragma unroll
    for (int n = 0; n < 4; ++n) acc[m][n] = (f32x4){0.f, 0.f, 0.f, 0.f};
  gemm_core(x_h + (long)row0 * 512, wq + (long)col0 * 512, 512, 512, 16,
            16703 - row0, As, Bs, acc);
  const int lane = threadIdx.x & 63, wave = threadIdx.x >> 6;
  const int wr = wave >> 1, wc = wave & 1, fr = lane & 15, fg = lane >> 4;
  float ba[4], bsh[4];
  int chs[4];
  #pragma unroll
  for (int n = 0; n < 4; ++n) {
    int ch = col0 + wc * 64 + n * 16 + fr;
    chs[n] = ch; ba[n] = bn_a[ch]; bsh[n] = bn_sh[ch];
  }
  #pragma unroll
  for (int m = 0; m < 4; ++m) {
    #pragma unroll
    for (int rr = 0; rr < 4; ++rr) {
      int row = row0 + wr * 64 + m * 16 + fg * 4 + rr;
      if (row < 16704) {
        int bi = row / 1044;
        int ni = row - bi * 1044;
        #pragma unroll
        for (int n = 0; n < 4; ++n) {
          float val = acc[m][n][rr] * ba[n] + bsh[n];
          int ch = chs[n];
          int hh = ch >> 7, r = ch & 127;
          long bh = (long)(bi * 8 + hh);
          if (r < 32)      qb[(bh * 1152 + ni) * 32 + r] = (f16)(val * QSCALE);
          else if (r < 64) kb[(bh * 1088 + ni) * 32 + (r - 32)] = (f16)val;
          else             vt[(bh * 64 + (r - 64)) * 1088 + ni] = (f16)val;
        }
      }
    }
  }
}

// ---------------------------------------------------------------------------
// depthwise conv branch (round-3 verbatim)
// ---------------------------------------------------------------------------
__global__ __launch_bounds__(256) void conv_kernel(
    const f16* __restrict__ vt, const float* __restrict__ conv_w,
    const float* __restrict__ conv_b, f16* __restrict__ vcT)
{
  __shared__ f16 img[16][34][36];
  const int b = blockIdx.y, g = blockIdx.x;
  const int c0 = g * 16, h = c0 >> 6, ci0 = c0 & 63;
  const int t = threadIdx.x;
  for (int i = t; i < 16 * 34 * 36; i += 256) ((f16*)img)[i] = (f16)0.f;
  __syncthreads();
  const int d = t >> 2, seg = t & 3;
  const f16* src = vt + ((long)(b * 8 + h) * 64 + d) * 1088 + ci0 * 16 + seg * 64;
  const int dhib = d >> 5;
  const int s2 = d & 31;
  #pragma unroll
  for (int j = 0; j < 8; ++j) {
    f16x8 vv = *(const f16x8*)(src + j * 8);
    #pragma unroll
    for (int e = 0; e < 8; ++e) {
      int local = seg * 64 + j * 8 + e;
      int cl = local >> 4, rr = local & 15;
      float xv = (float)vv[e];
      float hs = xv * fminf(fmaxf(xv + 3.f, 0.f), 6.f) * (1.f / 6.f);
      img[cl][1 + rr * 2 + dhib][1 + s2] = (f16)hs;
    }
  }
  __syncthreads();
  const int cl = t & 15, pg = t >> 4;
  const int c = c0 + cl;
  float w[9];
  #pragma unroll
  for (int i = 0; i < 9; ++i) w[i] = conv_w[c * 9 + i];
  const float bias = conv_b[c];
  for (int i = 0; i < 64; ++i) {
    int p = pg + i * 16;
    int s1 = p >> 5, ss2 = p & 31;
    float a = bias;
    #pragma unroll
    for (int di = 0; di < 3; ++di)
      #pragma unroll
      for (int dj = 0; dj < 3; ++dj)
        a += w[di * 3 + dj] * (float)img[cl][s1 + di][ss2 + dj];
    vcT[((long)b * 1024 + p) * 512 + c] = (f16)a;
  }
}

// ---------------------------------------------------------------------------
// fused attention (round-3 verbatim)
// ---------------------------------------------------------------------------
__global__ __launch_bounds__(256) void attn_kernel(
    const f16* __restrict__ qb, const f16* __restrict__ kb,
    const f16* __restrict__ vt, f16* __restrict__ opad)
{
  __shared__ f16 kls[2][4 * 64 * 8];
  __shared__ f16 vls[2][8 * 64 * 8];
  __shared__ float l_sh[4][32];

  const int id = blockIdx.x + blockIdx.y * 9;
  const int xcd = id & 7, sl = id >> 3;
  const int bh = xcd * 16 + sl / 9, qblk = sl % 9;
  const int b = bh >> 3, h = bh & 7;
  const int t = threadIdx.x;
  const int wave = t >> 6, lane = t & 63;
  const int lq = lane & 31, hi = lane >> 5;
  const int q0 = qblk * 128 + wave * 32;

  const f16* qb_ = qb + (long)bh * 1152 * 32;
  const f16* kb_ = kb + (long)bh * 1088 * 32;
  const f16* vt_ = vt + (long)bh * 64 * 1088;

  const f16x8 qf0 = *(const f16x8*)(qb_ + (long)(q0 + lq) * 32 + hi * 8);
  const f16x8 qf1 = *(const f16x8*)(qb_ + (long)(q0 + lq) * 32 + 16 + hi * 8);

  const int sk_k = t >> 2, sk_s = t & 3;
  const int sv_d = t >> 3, sv_p = t & 7;
  const int wkoff  = (sk_s * 64 + ((sk_k + sk_s) & 63)) * 16;
  const int wvoff0 = (sv_p * 64 + ((sv_d + sv_p) & 63)) * 16;
  const int wvoff1 = (sv_p * 64 + ((sv_d + 32 + sv_p) & 63)) * 16;
  int koff[2][2], voff[2][4];
  #pragma unroll
  for (int blk = 0; blk < 2; ++blk)
    #pragma unroll
    for (int ss = 0; ss < 2; ++ss) {
      int ss2 = 2 * ss + hi;
      koff[blk][ss] = (ss2 * 64 + ((blk * 32 + lq + ss2) & 63)) * 16;
    }
  #pragma unroll
  for (int nd = 0; nd < 2; ++nd)
    #pragma unroll
    for (int ks = 0; ks < 4; ++ks) {
      int kk8 = 2 * ks + hi;
      voff[nd][ks] = (kk8 * 64 + ((nd * 32 + lq + kk8) & 63)) * 16;
    }

  f16x8 stk, stv0, stv1;
  auto load_tile = [&](int kt) {
    stk  = *(const f16x8*)(kb_ + (long)(kt * 64 + sk_k) * 32 + sk_s * 8);
    stv0 = *(const f16x8*)(vt_ + (long)sv_d * 1088 + kt * 64 + sv_p * 8);
    stv1 = *(const f16x8*)(vt_ + (long)(sv_d + 32) * 1088 + kt * 64 + sv_p * 8);
  };
  auto write_tile = [&](int buf) {
    *(f16x8*)((char*)kls[buf] + wkoff)  = stk;
    *(f16x8*)((char*)vls[buf] + wvoff0) = stv0;
    *(f16x8*)((char*)vls[buf] + wvoff1) = stv1;
  };

  f32x16 o0 = zero16(), o1 = zero16();
  float lsum = 0.f;

  load_tile(0);
  write_tile(0);
  __syncthreads();

  int cur = 0;
  #pragma unroll 1
  for (int kt = 0; kt < 17; ++kt) {
    if (kt < 16) load_tile(kt + 1);
    const char* kcur = (const char*)kls[cur];
    const char* vcur = (const char*)vls[cur];
    f16x8 kf[2][2];
    #pragma unroll
    for (int blk = 0; blk < 2; ++blk)
      #pragma unroll
      for (int ss = 0; ss < 2; ++ss)
        kf[blk][ss] = *(const f16x8*)(kcur + koff[blk][ss]);
    f32x16 s0 = zero16(), s1 = zero16();
    s0 = __builtin_amdgcn_mfma_f32_32x32x16_f16(kf[0][0], qf0, s0, 0, 0, 0);
    s0 = __builtin_amdgcn_mfma_f32_32x32x16_f16(kf[0][1], qf1, s0, 0, 0, 0);
    s1 = __builtin_amdgcn_mfma_f32_32x32x16_f16(kf[1][0], qf0, s1, 0, 0, 0);
    s1 = __builtin_amdgcn_mfma_f32_32x32x16_f16(kf[1][1], qf1, s1, 0, 0, 0);
    float p0[16], p1[16];
    #pragma unroll
    for (int r = 0; r < 16; ++r) { p0[r] = EXP2(s0[r]); p1[r] = EXP2(s1[r]); }
    if (kt == 16) {
      #pragma unroll
      for (int r = 0; r < 16; ++r) {
        int cr = (r & 3) + 8 * (r >> 2) + 4 * hi;
        p0[r] = (cr < 20) ? p0[r] : 0.f;
        p1[r] = 0.f;
      }
    }
    float t8[8];
    #pragma unroll
    for (int r = 0; r < 8; ++r) t8[r] = (p0[r] + p0[r + 8]) + (p1[r] + p1[r + 8]);
    lsum += ((t8[0] + t8[1]) + (t8[2] + t8[3])) + ((t8[4] + t8[5]) + (t8[6] + t8[7]));
    f16x8 pa[4];
    pack_block(p0, pa[0], pa[1]);
    pack_block(p1, pa[2], pa[3]);
    #pragma unroll
    for (int ks = 0; ks < 4; ++ks) {
      f16x8 vf0 = *(const f16x8*)(vcur + voff[0][ks]);
      f16x8 vf1 = *(const f16x8*)(vcur + voff[1][ks]);
      o0 = __builtin_amdgcn_mfma_f32_32x32x16_f16(pa[ks], vf0, o0, 0, 0, 0);
      o1 = __builtin_amdgcn_mfma_f32_32x32x16_f16(pa[ks], vf1, o1, 0, 0, 0);
    }
    if (kt < 16) write_tile(cur ^ 1);
    __syncthreads();
    cur ^= 1;
  }

  lsum += __shfl_xor(lsum, 32);
  l_sh[wave][lq] = lsum;
  __syncthreads();
  float invl[16];
  #pragma unroll
  for (int r = 0; r < 16; ++r) {
    int cr = (r & 3) + 8 * (r >> 2) + 4 * hi;
    invl[r] = __builtin_amdgcn_rcpf(l_sh[wave][cr]);
  }
  #pragma unroll
  for (int nd = 0; nd < 2; ++nd) {
    #pragma unroll
    for (int r = 0; r < 16; ++r) {
      int cr = (r & 3) + 8 * (r >> 2) + 4 * hi;
      int q = q0 + cr;
      if (q < 1044) {
        float val = (nd ? o1[r] : o0[r]) * invl[r];
        unsigned flat = (unsigned)q * 512u + (unsigned)h * 64u + (unsigned)(nd * 32 + lq);
        unsigned c = flat / 1044u;
        unsigned np = flat - c * 1044u;
        opad[((long)b * 512 + c) * 1056 + np] = (f16)val;
      }
    }
  }
}

// ---------------------------------------------------------------------------
// proj GEMM (round-3 verbatim + XCD block remap).  grid dim3(4,8,16)
// ---------------------------------------------------------------------------
__global__ __launch_bounds__(256) void proj_gemm(
    const f16* __restrict__ pw, const f16* __restrict__ opad,
    const float* __restrict__ proj_b, const f16* __restrict__ vcT,
    f16* __restrict__ xoT)
{
  __shared__ f16 As[128 * 40];
  __shared__ f16 Bs[128 * 40];
  const int id = blockIdx.x + blockIdx.y * 4 + blockIdx.z * 32;  // [0,512)
  const int lin = (id & 7) * 64 + (id >> 3);                     // bijective
  const int b = lin >> 5;
  const int rc = lin & 31;
  const int row0 = (rc >> 2) * 128;  // m (image pixel)
  const int col0 = (rc & 3) * 128;   // c (channel)
  f32x4 acc[4][4];
  #pragma unroll
  for (int m = 0; m < 4; ++m)
    #pragma unroll
    for (int n = 0; n < 4; ++n) acc[m][n] = (f32x4){0.f, 0.f, 0.f, 0.f};
  gemm_core(pw + (long)row0 * 1056, opad + ((long)b * 512 + col0) * 1056,
            1056, 1056, 33, 1 << 30, As, Bs, acc);
  const int lane = threadIdx.x & 63, wave = threadIdx.x >> 6;
  const int wr = wave >> 1, wc = wave & 1, fr = lane & 15, fg = lane >> 4;
  #pragma unroll
  for (int m = 0; m < 4; ++m) {
    #pragma unroll
    for (int rr = 0; rr < 4; ++rr) {
      int mi = row0 + wr * 64 + m * 16 + fg * 4 + rr;
      float pb = proj_b[mi];
      #pragma unroll
      for (int n = 0; n < 4; ++n) {
        int c = col0 + wc * 64 + n * 16 + fr;
        long idx = ((long)b * 1024 + mi) * 512 + c;
        xoT[idx] = (f16)(acc[m][n][rr] + pb + (float)vcT[idx]);
      }
    }
  }
}

// ---------------------------------------------------------------------------
// out GEMM (round-3 verbatim + XCD block remap).  grid dim3(4,8,16)
// ---------------------------------------------------------------------------
__global__ __launch_bounds__(256) void out_gemm(
    const f16* __restrict__ xoT, const f16* __restrict__ ow,
    const float* __restrict__ out_b, float* __restrict__ out)
{
  __shared__ f16 As[128 * 40];
  __shared__ f16 Bs[128 * 40];
  const int id = blockIdx.x + blockIdx.y * 4 + blockIdx.z * 32;  // [0,512)
  const int lin = (id & 7) * 64 + (id >> 3);                     // bijective
  const int b = lin >> 5;
  const int rc = lin & 31;
  const int row0 = (rc >> 2) * 128;
  const int col0 = (rc & 3) * 128;
  f32x4 acc[4][4];
  #pragma unroll
  for (int m = 0; m < 4; ++m)
    #pragma unroll
    for (int n = 0; n < 4; ++n) acc[m][n] = (f32x4){0.f, 0.f, 0.f, 0.f};
  gemm_core(xoT + ((long)b * 1024 + row0) * 512, ow + (long)col0 * 512,
            512, 512, 16, 1 << 30, As, Bs, acc);
  const int lane = threadIdx.x & 63, wave = threadIdx.x >> 6;
  const int wr = wave >> 1, wc = wave & 1, fr = lane & 15, fg = lane >> 4;
  float ob[4];
  #pragma unroll
  for (int n = 0; n < 4; ++n) ob[n] = out_b[col0 + wc * 64 + n * 16 + fr];
  #pragma unroll
  for (int m = 0; m < 4; ++m) {
    #pragma unroll
    for (int rr = 0; rr < 4; ++rr) {
      int mi = row0 + wr * 64 + m * 16 + fg * 4 + rr;
      #pragma unroll
      for (int n = 0; n < 4; ++n) {
        int co = col0 + wc * 64 + n * 16 + fr;
        out[((long)b * 1024 + mi) * 512 + co] = acc[m][n][rr] + ob[n];
      }
    }
  }
}

// ---------------------------------------------------------------------------
extern "C" void kernel_launch(void* const* d_in, const int* in_sizes, int n_in,
                              void* d_out, int out_size, void* d_ws, size_t ws_size,
                              hipStream_t stream) {
  const float* x      = (const float*)d_in[0];
  const float* qkv_w  = (const float*)d_in[1];
  const float* bn_g   = (const float*)d_in[2];
  const float* bn_b   = (const float*)d_in[3];
  const float* bn_m   = (const float*)d_in[4];
  const float* bn_v   = (const float*)d_in[5];
  const float* conv_w = (const float*)d_in[6];
  const float* conv_b = (const float*)d_in[7];
  const float* proj_w = (const float*)d_in[8];
  const float* proj_b = (const float*)d_in[9];
  const float* out_w  = (const float*)d_in[10];
  const float* out_b  = (const float*)d_in[11];
  float* out = (float*)d_out;

  char* ws = (char*)d_ws;
  f16*   x_h   = (f16*)(ws + OFF_XH);
  f16*   wq_h  = (f16*)(ws + OFF_WQ);
  f16*   pw_h  = (f16*)(ws + OFF_PW);
  f16*   ow_h  = (f16*)(ws + OFF_OW);
  float* bn_a  = (float*)(ws + OFF_BNA);
  float* bn_sh = (float*)(ws + OFF_BNB);
  f16*   qb    = (f16*)(ws + OFF_QB);
  f16*   kb    = (f16*)(ws + OFF_KB);
  f16*   vt    = (f16*)(ws + OFF_VT);
  f16*   opad  = (f16*)(ws + OFF_OPAD);
  f16*   vcT   = (f16*)(ws + OFF_VCT);
  f16*   xoT   = (f16*)(ws + OFF_XOT);

  prep_kernel<<<1024, 256, 0, stream>>>(x, qkv_w, bn_g, bn_b, bn_m, bn_v,
                                        proj_w, out_w, x_h, wq_h, pw_h, ow_h,
                                        bn_a, bn_sh, qb, kb, vt, opad);
  qkv_gemm<<<dim3(8, 131), 256, 0, stream>>>(x_h, wq_h, bn_a, bn_sh, qb, kb, vt);
  conv_kernel<<<dim3(32, 16), 256, 0, stream>>>(vt, conv_w, conv_b, vcT);
  attn_kernel<<<dim3(9, 128), 256, 0, stream>>>(qb, kb, vt, opad);
  proj_gemm<<<dim3(4, 8, 16), 256, 0, stream>>>(pw_h, opad, proj_b, vcT, xoT);
  out_gemm<<<dim3(4, 8, 16), 256, 0, stream>>>(xoT, ow_h, out_b, out);
}

// Round 7
// 187.402 us; speedup vs baseline: 1.6473x; 1.0301x over previous
//
#include <hip/hip_runtime.h>
#include <hip/hip_fp16.h>

typedef _Float16 f16;
typedef _Float16 f16x8 __attribute__((ext_vector_type(8)));
typedef _Float16 f16x4 __attribute__((ext_vector_type(4)));
typedef float    f32x4 __attribute__((ext_vector_type(4)));
typedef float    f32x16 __attribute__((ext_vector_type(16)));

#define DEV __device__ __forceinline__

DEV int imin(int a, int b) { return a < b ? a : b; }

#if defined(__has_builtin)
#  if __has_builtin(__builtin_amdgcn_exp2f)
#    define EXP2(x) __builtin_amdgcn_exp2f(x)
#  else
#    define EXP2(x) __expf((x) * 0.6931471805599453f)
#  endif
#else
#  define EXP2(x) __expf((x) * 0.6931471805599453f)
#endif

// q pre-scale: (1/sqrt(32)) * log2(e) so softmax is p = 2^s
#define QSCALE (0.17677669529663687f * 1.4426950408889634f)

// ---------------------------------------------------------------------------
// Problem constants: B=16, N=1044, DIM=512, H=8, KD=32, D=64
// q padded to 1152 rows, k/v to 1088, o cols to 1056   (round-3/6 layout)
// ---------------------------------------------------------------------------

// workspace offsets (bytes) — round-3/6 proven layout
constexpr size_t OFF_XH   = 0;            // x fp16 (16704,512)          17,104,896
constexpr size_t OFF_WQ   = 17104896;     // qkv_w fp16 (1024,512)        1,048,576
constexpr size_t OFF_PW   = 18153472;     // proj_w fp16 (1024,1056)      2,162,688
constexpr size_t OFF_OW   = 20316160;     // out_w fp16 (512,512)           524,288
constexpr size_t OFF_BNA  = 20840448;     // bn scale fp32 (1024)
constexpr size_t OFF_BNB  = 20844544;     // bn shift fp32 (1024)
constexpr size_t OFF_QB   = 20848640;     // q fp16 (128,1152,32)         9,437,184
constexpr size_t OFF_KB   = 30285824;     // k fp16 (128,1088,32)         8,912,896
constexpr size_t OFF_VT   = 39198720;     // v^T fp16 (128,64,1088)      17,825,792
constexpr size_t OFF_OPAD = 57024512;     // o fp16 (16,512,1056)        17,301,504
constexpr size_t OFF_VCT  = 74326016;     // vcT fp16 (16,1024,512)      16,777,216
constexpr size_t OFF_XOT  = 91103232;     // xoT fp16 (16,1024,512)      16,777,216

DEV f32x16 zero16() {
  f32x16 z;
  #pragma unroll
  for (int i = 0; i < 16; ++i) z[i] = 0.f;
  return z;
}

DEV unsigned pk2(float a, float b) {
  auto h = __builtin_amdgcn_cvt_pkrtz(a, b);
  union { decltype(h) x; unsigned u; } t;
  t.x = h;
  return t.u;
}

DEV void plswap(unsigned &a, unsigned &b) {
  asm("v_permlane32_swap_b32 %0, %1" : "+v"(a), "+v"(b));
}

union W4 { unsigned w[4]; f16x8 v; };

DEV void pack_block(const float p[16], f16x8 &a0, f16x8 &a1) {
  unsigned w0 = pk2(p[0], p[1]),   w1 = pk2(p[2], p[3]);
  unsigned w2 = pk2(p[4], p[5]),   w3 = pk2(p[6], p[7]);
  unsigned w4 = pk2(p[8], p[9]),   w5 = pk2(p[10], p[11]);
  unsigned w6 = pk2(p[12], p[13]), w7 = pk2(p[14], p[15]);
  plswap(w0, w2); plswap(w1, w3);
  plswap(w4, w6); plswap(w5, w7);
  W4 u; u.w[0] = w0; u.w[1] = w1; u.w[2] = w2; u.w[3] = w3; a0 = u.v;
  W4 v; v.w[0] = w4; v.w[1] = w5; v.w[2] = w6; v.w[3] = w7; a1 = v.v;
}

// ---------------------------------------------------------------------------
// prep: fp32->fp16 conversions, BN fold, zero pads   (round-3/6 verbatim)
// ---------------------------------------------------------------------------
__global__ __launch_bounds__(256) void prep_kernel(
    const float* __restrict__ x, const float* __restrict__ qkv_w,
    const float* __restrict__ bn_g, const float* __restrict__ bn_b,
    const float* __restrict__ bn_m, const float* __restrict__ bn_v,
    const float* __restrict__ proj_w, const float* __restrict__ out_w,
    f16* __restrict__ x_h, f16* __restrict__ wq_h, f16* __restrict__ pw_h,
    f16* __restrict__ ow_h, float* __restrict__ bn_a, float* __restrict__ bn_sh,
    f16* __restrict__ qb, f16* __restrict__ kb, f16* __restrict__ vt,
    f16* __restrict__ opad)
{
  long tid = (long)blockIdx.x * blockDim.x + threadIdx.x;
  long gsz = (long)gridDim.x * blockDim.x;

  for (long i = tid; i < 2138112; i += gsz) {
    float4 f = ((const float4*)x)[i];
    f16x4 o = {(f16)f.x, (f16)f.y, (f16)f.z, (f16)f.w};
    ((f16x4*)x_h)[i] = o;
  }
  for (long i = tid; i < 524288; i += gsz) wq_h[i] = (f16)qkv_w[i];
  for (long i = tid; i < 1081344; i += gsz) {
    long m = i / 1056, nn = i - m * 1056;
    pw_h[i] = (nn < 1044) ? (f16)proj_w[m * 1044 + nn] : (f16)0.f;
  }
  for (long i = tid; i < 262144; i += gsz) ow_h[i] = (f16)out_w[i];
  for (long i = tid; i < 1024; i += gsz) {
    float a = bn_g[i] * rsqrtf(bn_v[i] + 1e-5f);
    bn_a[i] = a;
    bn_sh[i] = bn_b[i] - bn_m[i] * a;
  }
  // qb pad rows 1044..1151
  for (long i = tid; i < 13824; i += gsz) {
    int bh = (int)(i / 108);
    int nn = 1044 + (int)(i - (long)bh * 108);
    f16* q = qb + ((long)bh * 1152 + nn) * 32;
    for (int j = 0; j < 32; ++j) q[j] = (f16)0.f;
  }
  // kb pad rows 1044..1087
  for (long i = tid; i < 5632; i += gsz) {
    int bh = (int)(i / 44);
    int nn = 1044 + (int)(i - (long)bh * 44);
    f16* k = kb + ((long)bh * 1088 + nn) * 32;
    for (int j = 0; j < 32; ++j) k[j] = (f16)0.f;
  }
  // vt pad cols 1044..1087
  for (long i = tid; i < 8192; i += gsz) {
    f16* v = vt + i * 1088 + 1044;
    for (int j = 0; j < 44; ++j) v[j] = (f16)0.f;
  }
  // opad pad cols 1044..1055
  for (long i = tid; i < 8192; i += gsz) {
    f16* o = opad + i * 1056 + 1044;
    for (int j = 0; j < 12; ++j) o[j] = (f16)0.f;
  }
}

// ---------------------------------------------------------------------------
// shared 128x128xK NT-GEMM core.  Round-6 addressing (BK=32, LDS stride 40,
// single buffer, 2 barriers) + T14 prefetch: loads for kt+1 issued AFTER
// barrier2 (hipcc drains vmcnt at barriers) so they overlap the MFMA phase
// and drain at barrier1 of kt+1, exactly where the store needs them.
// ---------------------------------------------------------------------------
DEV void gemm_core(const f16* __restrict__ A, const f16* __restrict__ B,
                   int lda, int ldb, int kIters, int rowClamp,
                   f16* As, f16* Bs, f32x4 acc[4][4])
{
  const int t = threadIdx.x;
  const int wave = t >> 6, lane = t & 63;
  const int wr = wave >> 1, wc = wave & 1;
  const int r0 = t >> 2, seg = t & 3;
  const int fr = lane & 15, fg = lane >> 4;
  const int ra0 = imin(r0, rowClamp);
  const int ra1 = imin(r0 + 64, rowClamp);

  const f16* pa0 = A + (long)ra0 * lda + seg * 8;
  const f16* pa1 = A + (long)ra1 * lda + seg * 8;
  const f16* pb0 = B + (long)r0 * ldb + seg * 8;
  const f16* pb1 = B + (long)(r0 + 64) * ldb + seg * 8;

  f16x8 a0, a1, b0, b1;
  // prologue: load tile 0
  a0 = *(const f16x8*)(pa0);
  a1 = *(const f16x8*)(pa1);
  b0 = *(const f16x8*)(pb0);
  b1 = *(const f16x8*)(pb1);

  #pragma unroll 1
  for (int kt = 0; kt < kIters; ++kt) {
    __syncthreads();   // barrier1: prev frag-reads done; prefetch loads drain
    *(f16x8*)(As + r0 * 40 + seg * 8) = a0;
    *(f16x8*)(As + (r0 + 64) * 40 + seg * 8) = a1;
    *(f16x8*)(Bs + r0 * 40 + seg * 8) = b0;
    *(f16x8*)(Bs + (r0 + 64) * 40 + seg * 8) = b1;
    __syncthreads();   // barrier2: stores visible
    if (kt + 1 < kIters) {
      const int kb = (kt + 1) * 32;
      a0 = *(const f16x8*)(pa0 + kb);
      a1 = *(const f16x8*)(pa1 + kb);
      b0 = *(const f16x8*)(pb0 + kb);
      b1 = *(const f16x8*)(pb1 + kb);
    }
    f16x8 af[4], bf[4];
    #pragma unroll
    for (int m = 0; m < 4; ++m)
      af[m] = *(const f16x8*)(As + (wr * 64 + m * 16 + fr) * 40 + fg * 8);
    #pragma unroll
    for (int n = 0; n < 4; ++n)
      bf[n] = *(const f16x8*)(Bs + (wc * 64 + n * 16 + fr) * 40 + fg * 8);
    #pragma unroll
    for (int m = 0; m < 4; ++m)
      #pragma unroll
      for (int n = 0; n < 4; ++n)
        acc[m][n] = __builtin_amdgcn_mfma_f32_16x16x32_f16(af[m], bf[n], acc[m][n], 0, 0, 0);
  }
}

// ---------------------------------------------------------------------------
// QKV GEMM + BN epilogue -> q (pre-scaled), k, v^T.  grid dim3(8,131);
// XCD-locality block remap (round-6 proven).
// ---------------------------------------------------------------------------
__global__ __launch_bounds__(256) void qkv_gemm(
    const f16* __restrict__ x_h, const f16* __restrict__ wq,
    const float* __restrict__ bn_a, const float* __restrict__ bn_sh,
    f16* __restrict__ qb, f16* __restrict__ kb, f16* __restrict__ vt)
{
  __shared__ f16 As[128 * 40];
  __shared__ f16 Bs[128 * 40];
  const int id = blockIdx.x + blockIdx.y * 8;          // [0,1048)
  const int lin = (id & 7) * 131 + (id >> 3);          // bijective [0,1048)
  const int row0 = (lin >> 3) * 128, col0 = (lin & 7) * 128;
  f32x4 acc[4][4];
  #pragma unroll
  for (int m = 0; m < 4; ++m)
    #pragma unroll
    for (int n = 0; n < 4; ++n) acc[m][n] = (f32x4){0.f, 0.f, 0.f, 0.f};
  gemm_core(x_h + (long)row0 * 512, wq + (long)col0 * 512, 512, 512, 16,
            16703 - row0, As, Bs, acc);
  const int lane = threadIdx.x & 63, wave = threadIdx.x >> 6;
  const int wr = wave >> 1, wc = wave & 1, fr = lane & 15, fg = lane >> 4;
  float ba[4], bsh[4];
  int chs[4];
  #pragma unroll
  for (int n = 0; n < 4; ++n) {
    int ch = col0 + wc * 64 + n * 16 + fr;
    chs[n] = ch; ba[n] = bn_a[ch]; bsh[n] = bn_sh[ch];
  }
  #pragma unroll
  for (int m = 0; m < 4; ++m) {
    #pragma unroll
    for (int rr = 0; rr < 4; ++rr) {
      int row = row0 + wr * 64 + m * 16 + fg * 4 + rr;
      if (row < 16704) {
        int bi = row / 1044;
        int ni = row - bi * 1044;
        #pragma unroll
        for (int n = 0; n < 4; ++n) {
          float val = acc[m][n][rr] * ba[n] + bsh[n];
          int ch = chs[n];
          int hh = ch >> 7, r = ch & 127;
          long bh = (long)(bi * 8 + hh);
          if (r < 32)      qb[(bh * 1152 + ni) * 32 + r] = (f16)(val * QSCALE);
          else if (r < 64) kb[(bh * 1088 + ni) * 32 + (r - 32)] = (f16)val;
          else             vt[(bh * 64 + (r - 64)) * 1088 + ni] = (f16)val;
        }
      }
    }
  }
}

// ---------------------------------------------------------------------------
// depthwise conv branch (round-3/6 verbatim)
// ---------------------------------------------------------------------------
__global__ __launch_bounds__(256) void conv_kernel(
    const f16* __restrict__ vt, const float* __restrict__ conv_w,
    const float* __restrict__ conv_b, f16* __restrict__ vcT)
{
  __shared__ f16 img[16][34][36];
  const int b = blockIdx.y, g = blockIdx.x;
  const int c0 = g * 16, h = c0 >> 6, ci0 = c0 & 63;
  const int t = threadIdx.x;
  for (int i = t; i < 16 * 34 * 36; i += 256) ((f16*)img)[i] = (f16)0.f;
  __syncthreads();
  const int d = t >> 2, seg = t & 3;
  const f16* src = vt + ((long)(b * 8 + h) * 64 + d) * 1088 + ci0 * 16 + seg * 64;
  const int dhib = d >> 5;
  const int s2 = d & 31;
  #pragma unroll
  for (int j = 0; j < 8; ++j) {
    f16x8 vv = *(const f16x8*)(src + j * 8);
    #pragma unroll
    for (int e = 0; e < 8; ++e) {
      int local = seg * 64 + j * 8 + e;
      int cl = local >> 4, rr = local & 15;
      float xv = (float)vv[e];
      float hs = xv * fminf(fmaxf(xv + 3.f, 0.f), 6.f) * (1.f / 6.f);
      img[cl][1 + rr * 2 + dhib][1 + s2] = (f16)hs;
    }
  }
  __syncthreads();
  const int cl = t & 15, pg = t >> 4;
  const int c = c0 + cl;
  float w[9];
  #pragma unroll
  for (int i = 0; i < 9; ++i) w[i] = conv_w[c * 9 + i];
  const float bias = conv_b[c];
  for (int i = 0; i < 64; ++i) {
    int p = pg + i * 16;
    int s1 = p >> 5, ss2 = p & 31;
    float a = bias;
    #pragma unroll
    for (int di = 0; di < 3; ++di)
      #pragma unroll
      for (int dj = 0; dj < 3; ++dj)
        a += w[di * 3 + dj] * (float)img[cl][s1 + di][ss2 + dj];
    vcT[((long)b * 1024 + p) * 512 + c] = (f16)a;
  }
}

// ---------------------------------------------------------------------------
// fused attention (round-3/6 verbatim)
// ---------------------------------------------------------------------------
__global__ __launch_bounds__(256) void attn_kernel(
    const f16* __restrict__ qb, const f16* __restrict__ kb,
    const f16* __restrict__ vt, f16* __restrict__ opad)
{
  __shared__ f16 kls[2][4 * 64 * 8];
  __shared__ f16 vls[2][8 * 64 * 8];
  __shared__ float l_sh[4][32];

  const int id = blockIdx.x + blockIdx.y * 9;
  const int xcd = id & 7, sl = id >> 3;
  const int bh = xcd * 16 + sl / 9, qblk = sl % 9;
  const int b = bh >> 3, h = bh & 7;
  const int t = threadIdx.x;
  const int wave = t >> 6, lane = t & 63;
  const int lq = lane & 31, hi = lane >> 5;
  const int q0 = qblk * 128 + wave * 32;

  const f16* qb_ = qb + (long)bh * 1152 * 32;
  const f16* kb_ = kb + (long)bh * 1088 * 32;
  const f16* vt_ = vt + (long)bh * 64 * 1088;

  const f16x8 qf0 = *(const f16x8*)(qb_ + (long)(q0 + lq) * 32 + hi * 8);
  const f16x8 qf1 = *(const f16x8*)(qb_ + (long)(q0 + lq) * 32 + 16 + hi * 8);

  const int sk_k = t >> 2, sk_s = t & 3;
  const int sv_d = t >> 3, sv_p = t & 7;
  const int wkoff  = (sk_s * 64 + ((sk_k + sk_s) & 63)) * 16;
  const int wvoff0 = (sv_p * 64 + ((sv_d + sv_p) & 63)) * 16;
  const int wvoff1 = (sv_p * 64 + ((sv_d + 32 + sv_p) & 63)) * 16;
  int koff[2][2], voff[2][4];
  #pragma unroll
  for (int blk = 0; blk < 2; ++blk)
    #pragma unroll
    for (int ss = 0; ss < 2; ++ss) {
      int ss2 = 2 * ss + hi;
      koff[blk][ss] = (ss2 * 64 + ((blk * 32 + lq + ss2) & 63)) * 16;
    }
  #pragma unroll
  for (int nd = 0; nd < 2; ++nd)
    #pragma unroll
    for (int ks = 0; ks < 4; ++ks) {
      int kk8 = 2 * ks + hi;
      voff[nd][ks] = (kk8 * 64 + ((nd * 32 + lq + kk8) & 63)) * 16;
    }

  f16x8 stk, stv0, stv1;
  auto load_tile = [&](int kt) {
    stk  = *(const f16x8*)(kb_ + (long)(kt * 64 + sk_k) * 32 + sk_s * 8);
    stv0 = *(const f16x8*)(vt_ + (long)sv_d * 1088 + kt * 64 + sv_p * 8);
    stv1 = *(const f16x8*)(vt_ + (long)(sv_d + 32) * 1088 + kt * 64 + sv_p * 8);
  };
  auto write_tile = [&](int buf) {
    *(f16x8*)((char*)kls[buf] + wkoff)  = stk;
    *(f16x8*)((char*)vls[buf] + wvoff0) = stv0;
    *(f16x8*)((char*)vls[buf] + wvoff1) = stv1;
  };

  f32x16 o0 = zero16(), o1 = zero16();
  float lsum = 0.f;

  load_tile(0);
  write_tile(0);
  __syncthreads();

  int cur = 0;
  #pragma unroll 1
  for (int kt = 0; kt < 17; ++kt) {
    if (kt < 16) load_tile(kt + 1);
    const char* kcur = (const char*)kls[cur];
    const char* vcur = (const char*)vls[cur];
    f16x8 kf[2][2];
    #pragma unroll
    for (int blk = 0; blk < 2; ++blk)
      #pragma unroll
      for (int ss = 0; ss < 2; ++ss)
        kf[blk][ss] = *(const f16x8*)(kcur + koff[blk][ss]);
    f32x16 s0 = zero16(), s1 = zero16();
    s0 = __builtin_amdgcn_mfma_f32_32x32x16_f16(kf[0][0], qf0, s0, 0, 0, 0);
    s0 = __builtin_amdgcn_mfma_f32_32x32x16_f16(kf[0][1], qf1, s0, 0, 0, 0);
    s1 = __builtin_amdgcn_mfma_f32_32x32x16_f16(kf[1][0], qf0, s1, 0, 0, 0);
    s1 = __builtin_amdgcn_mfma_f32_32x32x16_f16(kf[1][1], qf1, s1, 0, 0, 0);
    float p0[16], p1[16];
    #pragma unroll
    for (int r = 0; r < 16; ++r) { p0[r] = EXP2(s0[r]); p1[r] = EXP2(s1[r]); }
    if (kt == 16) {
      #pragma unroll
      for (int r = 0; r < 16; ++r) {
        int cr = (r & 3) + 8 * (r >> 2) + 4 * hi;
        p0[r] = (cr < 20) ? p0[r] : 0.f;
        p1[r] = 0.f;
      }
    }
    float t8[8];
    #pragma unroll
    for (int r = 0; r < 8; ++r) t8[r] = (p0[r] + p0[r + 8]) + (p1[r] + p1[r + 8]);
    lsum += ((t8[0] + t8[1]) + (t8[2] + t8[3])) + ((t8[4] + t8[5]) + (t8[6] + t8[7]));
    f16x8 pa[4];
    pack_block(p0, pa[0], pa[1]);
    pack_block(p1, pa[2], pa[3]);
    #pragma unroll
    for (int ks = 0; ks < 4; ++ks) {
      f16x8 vf0 = *(const f16x8*)(vcur + voff[0][ks]);
      f16x8 vf1 = *(const f16x8*)(vcur + voff[1][ks]);
      o0 = __builtin_amdgcn_mfma_f32_32x32x16_f16(pa[ks], vf0, o0, 0, 0, 0);
      o1 = __builtin_amdgcn_mfma_f32_32x32x16_f16(pa[ks], vf1, o1, 0, 0, 0);
    }
    if (kt < 16) write_tile(cur ^ 1);
    __syncthreads();
    cur ^= 1;
  }

  lsum += __shfl_xor(lsum, 32);
  l_sh[wave][lq] = lsum;
  __syncthreads();
  float invl[16];
  #pragma unroll
  for (int r = 0; r < 16; ++r) {
    int cr = (r & 3) + 8 * (r >> 2) + 4 * hi;
    invl[r] = __builtin_amdgcn_rcpf(l_sh[wave][cr]);
  }
  #pragma unroll
  for (int nd = 0; nd < 2; ++nd) {
    #pragma unroll
    for (int r = 0; r < 16; ++r) {
      int cr = (r & 3) + 8 * (r >> 2) + 4 * hi;
      int q = q0 + cr;
      if (q < 1044) {
        float val = (nd ? o1[r] : o0[r]) * invl[r];
        unsigned flat = (unsigned)q * 512u + (unsigned)h * 64u + (unsigned)(nd * 32 + lq);
        unsigned c = flat / 1044u;
        unsigned np = flat - c * 1044u;
        opad[((long)b * 512 + c) * 1056 + np] = (f16)val;
      }
    }
  }
}

// ---------------------------------------------------------------------------
// proj GEMM (round-6 structure + new core).  grid dim3(4,8,16)
// ---------------------------------------------------------------------------
__global__ __launch_bounds__(256) void proj_gemm(
    const f16* __restrict__ pw, const f16* __restrict__ opad,
    const float* __restrict__ proj_b, const f16* __restrict__ vcT,
    f16* __restrict__ xoT)
{
  __shared__ f16 As[128 * 40];
  __shared__ f16 Bs[128 * 40];
  const int id = blockIdx.x + blockIdx.y * 4 + blockIdx.z * 32;  // [0,512)
  const int lin = (id & 7) * 64 + (id >> 3);                     // bijective
  const int b = lin >> 5;
  const int rc = lin & 31;
  const int row0 = (rc >> 2) * 128;  // m (image pixel)
  const int col0 = (rc & 3) * 128;   // c (channel)
  f32x4 acc[4][4];
  #pragma unroll
  for (int m = 0; m < 4; ++m)
    #pragma unroll
    for (int n = 0; n < 4; ++n) acc[m][n] = (f32x4){0.f, 0.f, 0.f, 0.f};
  gemm_core(pw + (long)row0 * 1056, opad + ((long)b * 512 + col0) * 1056,
            1056, 1056, 33, 1 << 30, As, Bs, acc);
  const int lane = threadIdx.x & 63, wave = threadIdx.x >> 6;
  const int wr = wave >> 1, wc = wave & 1, fr = lane & 15, fg = lane >> 4;
  #pragma unroll
  for (int m = 0; m < 4; ++m) {
    #pragma unroll
    for (int rr = 0; rr < 4; ++rr) {
      int mi = row0 + wr * 64 + m * 16 + fg * 4 + rr;
      float pb = proj_b[mi];
      #pragma unroll
      for (int n = 0; n < 4; ++n) {
        int c = col0 + wc * 64 + n * 16 + fr;
        long idx = ((long)b * 1024 + mi) * 512 + c;
        xoT[idx] = (f16)(acc[m][n][rr] + pb + (float)vcT[idx]);
      }
    }
  }
}

// ---------------------------------------------------------------------------
// out GEMM (round-6 structure + new core).  grid dim3(4,8,16)
// ---------------------------------------------------------------------------
__global__ __launch_bounds__(256) void out_gemm(
    const f16* __restrict__ xoT, const f16* __restrict__ ow,
    const float* __restrict__ out_b, float* __restrict__ out)
{
  __shared__ f16 As[128 * 40];
  __shared__ f16 Bs[128 * 40];
  const int id = blockIdx.x + blockIdx.y * 4 + blockIdx.z * 32;  // [0,512)
  const int lin = (id & 7) * 64 + (id >> 3);                     // bijective
  const int b = lin >> 5;
  const int rc = lin & 31;
  const int row0 = (rc >> 2) * 128;
  const int col0 = (rc & 3) * 128;
  f32x4 acc[4][4];
  #pragma unroll
  for (int m = 0; m < 4; ++m)
    #pragma unroll
    for (int n = 0; n < 4; ++n) acc[m][n] = (f32x4){0.f, 0.f, 0.f, 0.f};
  gemm_core(xoT + ((long)b * 1024 + row0) * 512, ow + (long)col0 * 512,
            512, 512, 16, 1 << 30, As, Bs, acc);
  const int lane = threadIdx.x & 63, wave = threadIdx.x >> 6;
  const int wr = wave >> 1, wc = wave & 1, fr = lane & 15, fg = lane >> 4;
  float ob[4];
  #pragma unroll
  for (int n = 0; n < 4; ++n) ob[n] = out_b[col0 + wc * 64 + n * 16 + fr];
  #pragma unroll
  for (int m = 0; m < 4; ++m) {
    #pragma unroll
    for (int rr = 0; rr < 4; ++rr) {
      int mi = row0 + wr * 64 + m * 16 + fg * 4 + rr;
      #pragma unroll
      for (int n = 0; n < 4; ++n) {
        int co = col0 + wc * 64 + n * 16 + fr;
        out[((long)b * 1024 + mi) * 512 + co] = acc[m][n][rr] + ob[n];
      }
    }
  }
}

// ---------------------------------------------------------------------------
extern "C" void kernel_launch(void* const* d_in, const int* in_sizes, int n_in,
                              void* d_out, int out_size, void* d_ws, size_t ws_size,
                              hipStream_t stream) {
  const float* x      = (const float*)d_in[0];
  const float* qkv_w  = (const float*)d_in[1];
  const float* bn_g   = (const float*)d_in[2];
  const float* bn_b   = (const float*)d_in[3];
  const float* bn_m   = (const float*)d_in[4];
  const float* bn_v   = (const float*)d_in[5];
  const float* conv_w = (const float*)d_in[6];
  const float* conv_b = (const float*)d_in[7];
  const float* proj_w = (const float*)d_in[8];
  const float* proj_b = (const float*)d_in[9];
  const float* out_w  = (const float*)d_in[10];
  const float* out_b  = (const float*)d_in[11];
  float* out = (float*)d_out;

  char* ws = (char*)d_ws;
  f16*   x_h   = (f16*)(ws + OFF_XH);
  f16*   wq_h  = (f16*)(ws + OFF_WQ);
  f16*   pw_h  = (f16*)(ws + OFF_PW);
  f16*   ow_h  = (f16*)(ws + OFF_OW);
  float* bn_a  = (float*)(ws + OFF_BNA);
  float* bn_sh = (float*)(ws + OFF_BNB);
  f16*   qb    = (f16*)(ws + OFF_QB);
  f16*   kb    = (f16*)(ws + OFF_KB);
  f16*   vt    = (f16*)(ws + OFF_VT);
  f16*   opad  = (f16*)(ws + OFF_OPAD);
  f16*   vcT   = (f16*)(ws + OFF_VCT);
  f16*   xoT   = (f16*)(ws + OFF_XOT);

  prep_kernel<<<1024, 256, 0, stream>>>(x, qkv_w, bn_g, bn_b, bn_m, bn_v,
                                        proj_w, out_w, x_h, wq_h, pw_h, ow_h,
                                        bn_a, bn_sh, qb, kb, vt, opad);
  qkv_gemm<<<dim3(8, 131), 256, 0, stream>>>(x_h, wq_h, bn_a, bn_sh, qb, kb, vt);
  conv_kernel<<<dim3(32, 16), 256, 0, stream>>>(vt, conv_w, conv_b, vcT);
  attn_kernel<<<dim3(9, 128), 256, 0, stream>>>(qb, kb, vt, opad);
  proj_gemm<<<dim3(4, 8, 16), 256, 0, stream>>>(pw_h, opad, proj_b, vcT, xoT);
  out_gemm<<<dim3(4, 8, 16), 256, 0, stream>>>(xoT, ow_h, out_b, out);
}

// Round 8
// 175.287 us; speedup vs baseline: 1.7612x; 1.0691x over previous
//
#include <hip/hip_runtime.h>
#include <hip/hip_fp16.h>

typedef _Float16 f16;
typedef _Float16 f16x8 __attribute__((ext_vector_type(8)));
typedef _Float16 f16x4 __attribute__((ext_vector_type(4)));
typedef float    f32x4 __attribute__((ext_vector_type(4)));
typedef float    f32x16 __attribute__((ext_vector_type(16)));

#define DEV __device__ __forceinline__

DEV int imin(int a, int b) { return a < b ? a : b; }

#if defined(__has_builtin)
#  if __has_builtin(__builtin_amdgcn_exp2f)
#    define EXP2(x) __builtin_amdgcn_exp2f(x)
#  else
#    define EXP2(x) __expf((x) * 0.6931471805599453f)
#  endif
#else
#  define EXP2(x) __expf((x) * 0.6931471805599453f)
#endif

// q pre-scale: (1/sqrt(32)) * log2(e) so softmax is p = 2^s
#define QSCALE (0.17677669529663687f * 1.4426950408889634f)

// ---------------------------------------------------------------------------
// Problem constants: B=16, N=1044, DIM=512, H=8, KD=32, D=64
// q padded to 1152 rows, k/v to 1088, o cols to 1056   (round-3/6 layout)
// ---------------------------------------------------------------------------

// workspace offsets (bytes) — round-3/6 proven layout
constexpr size_t OFF_XH   = 0;            // x fp16 (16704,512)          17,104,896
constexpr size_t OFF_WQ   = 17104896;     // qkv_w fp16 (1024,512)        1,048,576
constexpr size_t OFF_PW   = 18153472;     // proj_w fp16 (1024,1056)      2,162,688
constexpr size_t OFF_OW   = 20316160;     // out_w fp16 (512,512)           524,288
constexpr size_t OFF_BNA  = 20840448;     // bn scale fp32 (1024)
constexpr size_t OFF_BNB  = 20844544;     // bn shift fp32 (1024)
constexpr size_t OFF_QB   = 20848640;     // q fp16 (128,1152,32)         9,437,184
constexpr size_t OFF_KB   = 30285824;     // k fp16 (128,1088,32)         8,912,896
constexpr size_t OFF_VT   = 39198720;     // v^T fp16 (128,64,1088)      17,825,792
constexpr size_t OFF_OPAD = 57024512;     // o fp16 (16,512,1056)        17,301,504
constexpr size_t OFF_VCT  = 74326016;     // vcT fp16 (16,1024,512)      16,777,216
constexpr size_t OFF_XOT  = 91103232;     // xoT fp16 (16,1024,512)      16,777,216

DEV f32x16 zero16() {
  f32x16 z;
  #pragma unroll
  for (int i = 0; i < 16; ++i) z[i] = 0.f;
  return z;
}

DEV unsigned pk2(float a, float b) {
  auto h = __builtin_amdgcn_cvt_pkrtz(a, b);
  union { decltype(h) x; unsigned u; } t;
  t.x = h;
  return t.u;
}

DEV void plswap(unsigned &a, unsigned &b) {
  asm("v_permlane32_swap_b32 %0, %1" : "+v"(a), "+v"(b));
}

union W4 { unsigned w[4]; f16x8 v; };

DEV void pack_block(const float p[16], f16x8 &a0, f16x8 &a1) {
  unsigned w0 = pk2(p[0], p[1]),   w1 = pk2(p[2], p[3]);
  unsigned w2 = pk2(p[4], p[5]),   w3 = pk2(p[6], p[7]);
  unsigned w4 = pk2(p[8], p[9]),   w5 = pk2(p[10], p[11]);
  unsigned w6 = pk2(p[12], p[13]), w7 = pk2(p[14], p[15]);
  plswap(w0, w2); plswap(w1, w3);
  plswap(w4, w6); plswap(w5, w7);
  W4 u; u.w[0] = w0; u.w[1] = w1; u.w[2] = w2; u.w[3] = w3; a0 = u.v;
  W4 v; v.w[0] = w4; v.w[1] = w5; v.w[2] = w6; v.w[3] = w7; a1 = v.v;
}

// ---------------------------------------------------------------------------
// prep: fp32->fp16 conversions, BN fold, zero pads   (round-3/6 verbatim)
// ---------------------------------------------------------------------------
__global__ __launch_bounds__(256) void prep_kernel(
    const float* __restrict__ x, const float* __restrict__ qkv_w,
    const float* __restrict__ bn_g, const float* __restrict__ bn_b,
    const float* __restrict__ bn_m, const float* __restrict__ bn_v,
    const float* __restrict__ proj_w, const float* __restrict__ out_w,
    f16* __restrict__ x_h, f16* __restrict__ wq_h, f16* __restrict__ pw_h,
    f16* __restrict__ ow_h, float* __restrict__ bn_a, float* __restrict__ bn_sh,
    f16* __restrict__ qb, f16* __restrict__ kb, f16* __restrict__ vt,
    f16* __restrict__ opad)
{
  long tid = (long)blockIdx.x * blockDim.x + threadIdx.x;
  long gsz = (long)gridDim.x * blockDim.x;

  for (long i = tid; i < 2138112; i += gsz) {
    float4 f = ((const float4*)x)[i];
    f16x4 o = {(f16)f.x, (f16)f.y, (f16)f.z, (f16)f.w};
    ((f16x4*)x_h)[i] = o;
  }
  for (long i = tid; i < 524288; i += gsz) wq_h[i] = (f16)qkv_w[i];
  for (long i = tid; i < 1081344; i += gsz) {
    long m = i / 1056, nn = i - m * 1056;
    pw_h[i] = (nn < 1044) ? (f16)proj_w[m * 1044 + nn] : (f16)0.f;
  }
  for (long i = tid; i < 262144; i += gsz) ow_h[i] = (f16)out_w[i];
  for (long i = tid; i < 1024; i += gsz) {
    float a = bn_g[i] * rsqrtf(bn_v[i] + 1e-5f);
    bn_a[i] = a;
    bn_sh[i] = bn_b[i] - bn_m[i] * a;
  }
  // qb pad rows 1044..1151
  for (long i = tid; i < 13824; i += gsz) {
    int bh = (int)(i / 108);
    int nn = 1044 + (int)(i - (long)bh * 108);
    f16* q = qb + ((long)bh * 1152 + nn) * 32;
    for (int j = 0; j < 32; ++j) q[j] = (f16)0.f;
  }
  // kb pad rows 1044..1087
  for (long i = tid; i < 5632; i += gsz) {
    int bh = (int)(i / 44);
    int nn = 1044 + (int)(i - (long)bh * 44);
    f16* k = kb + ((long)bh * 1088 + nn) * 32;
    for (int j = 0; j < 32; ++j) k[j] = (f16)0.f;
  }
  // vt pad cols 1044..1087
  for (long i = tid; i < 8192; i += gsz) {
    f16* v = vt + i * 1088 + 1044;
    for (int j = 0; j < 44; ++j) v[j] = (f16)0.f;
  }
  // opad pad cols 1044..1055
  for (long i = tid; i < 8192; i += gsz) {
    f16* o = opad + i * 1056 + 1044;
    for (int j = 0; j < 12; ++j) o[j] = (f16)0.f;
  }
}

// ---------------------------------------------------------------------------
// shared 128x128xK NT-GEMM core (round-7 proven: BK=32, LDS stride 40, single
// buffer, 2 barriers, T14 prefetch after barrier2).  NEW: optional row clamp
// on B as well (for the transposed qkv where tokens are the B side).
// ---------------------------------------------------------------------------
DEV void gemm_core(const f16* __restrict__ A, const f16* __restrict__ B,
                   int lda, int ldb, int kIters, int rowClampA, int rowClampB,
                   f16* As, f16* Bs, f32x4 acc[4][4])
{
  const int t = threadIdx.x;
  const int wave = t >> 6, lane = t & 63;
  const int wr = wave >> 1, wc = wave & 1;
  const int r0 = t >> 2, seg = t & 3;
  const int fr = lane & 15, fg = lane >> 4;
  const int ra0 = imin(r0, rowClampA);
  const int ra1 = imin(r0 + 64, rowClampA);
  const int rb0 = imin(r0, rowClampB);
  const int rb1 = imin(r0 + 64, rowClampB);

  const f16* pa0 = A + (long)ra0 * lda + seg * 8;
  const f16* pa1 = A + (long)ra1 * lda + seg * 8;
  const f16* pb0 = B + (long)rb0 * ldb + seg * 8;
  const f16* pb1 = B + (long)rb1 * ldb + seg * 8;

  f16x8 a0, a1, b0, b1;
  // prologue: load tile 0
  a0 = *(const f16x8*)(pa0);
  a1 = *(const f16x8*)(pa1);
  b0 = *(const f16x8*)(pb0);
  b1 = *(const f16x8*)(pb1);

  #pragma unroll 1
  for (int kt = 0; kt < kIters; ++kt) {
    __syncthreads();   // barrier1: prev frag-reads done; prefetch loads drain
    *(f16x8*)(As + r0 * 40 + seg * 8) = a0;
    *(f16x8*)(As + (r0 + 64) * 40 + seg * 8) = a1;
    *(f16x8*)(Bs + r0 * 40 + seg * 8) = b0;
    *(f16x8*)(Bs + (r0 + 64) * 40 + seg * 8) = b1;
    __syncthreads();   // barrier2: stores visible
    if (kt + 1 < kIters) {
      const int kb = (kt + 1) * 32;
      a0 = *(const f16x8*)(pa0 + kb);
      a1 = *(const f16x8*)(pa1 + kb);
      b0 = *(const f16x8*)(pb0 + kb);
      b1 = *(const f16x8*)(pb1 + kb);
    }
    f16x8 af[4], bf[4];
    #pragma unroll
    for (int m = 0; m < 4; ++m)
      af[m] = *(const f16x8*)(As + (wr * 64 + m * 16 + fr) * 40 + fg * 8);
    #pragma unroll
    for (int n = 0; n < 4; ++n)
      bf[n] = *(const f16x8*)(Bs + (wc * 64 + n * 16 + fr) * 40 + fg * 8);
    #pragma unroll
    for (int m = 0; m < 4; ++m)
      #pragma unroll
      for (int n = 0; n < 4; ++n)
        acc[m][n] = __builtin_amdgcn_mfma_f32_16x16x32_f16(af[m], bf[n], acc[m][n], 0, 0, 0);
  }
}

// ---------------------------------------------------------------------------
// QKV GEMM, TRANSPOSED: A = wq (channels), B = x_h (tokens) ->
// C[ch][tok].  Epilogue: q/k vectorized f16x4 along the channel quad (rr),
// v^T lane-contiguous along tokens (fr).  grid dim3(8,131), XCD token-banded.
// ---------------------------------------------------------------------------
__global__ __launch_bounds__(256) void qkv_gemm(
    const f16* __restrict__ x_h, const f16* __restrict__ wq,
    const float* __restrict__ bn_a, const float* __restrict__ bn_sh,
    f16* __restrict__ qb, f16* __restrict__ kb, f16* __restrict__ vt)
{
  __shared__ f16 As[128 * 40];
  __shared__ f16 Bs[128 * 40];
  const int id = blockIdx.x + blockIdx.y * 8;          // [0,1048)
  const int lin = (id & 7) * 131 + (id >> 3);          // bijective [0,1048)
  const int row0 = (lin & 7) * 128;                    // channel block
  const int col0 = (lin >> 3) * 128;                   // token block (banded)
  f32x4 acc[4][4];
  #pragma unroll
  for (int m = 0; m < 4; ++m)
    #pragma unroll
    for (int n = 0; n < 4; ++n) acc[m][n] = (f32x4){0.f, 0.f, 0.f, 0.f};
  gemm_core(wq + (long)row0 * 512, x_h + (long)col0 * 512, 512, 512, 16,
            1 << 30, 16703 - col0, As, Bs, acc);
  const int lane = threadIdx.x & 63, wave = threadIdx.x >> 6;
  const int wr = wave >> 1, wc = wave & 1, fr = lane & 15, fg = lane >> 4;
  #pragma unroll
  for (int m = 0; m < 4; ++m) {
    const int chBase = row0 + wr * 64 + m * 16 + fg * 4;   // channel quad
    const float4 ba4 = *(const float4*)(bn_a + chBase);
    const float4 bs4 = *(const float4*)(bn_sh + chBase);
    const int hh = chBase >> 7, r = chBase & 127;          // quad-uniform cat
    #pragma unroll
    for (int n = 0; n < 4; ++n) {
      int tok = col0 + wc * 64 + n * 16 + fr;
      if (tok < 16704) {
        int bi = tok / 1044;
        int ni = tok - bi * 1044;
        long bh = (long)(bi * 8 + hh);
        float v0 = acc[m][n][0] * ba4.x + bs4.x;
        float v1 = acc[m][n][1] * ba4.y + bs4.y;
        float v2 = acc[m][n][2] * ba4.z + bs4.z;
        float v3 = acc[m][n][3] * ba4.w + bs4.w;
        if (r < 32) {
          f16x4 pk = {(f16)(v0 * QSCALE), (f16)(v1 * QSCALE),
                      (f16)(v2 * QSCALE), (f16)(v3 * QSCALE)};
          *(f16x4*)(qb + (bh * 1152 + ni) * 32 + r) = pk;
        } else if (r < 64) {
          f16x4 pk = {(f16)v0, (f16)v1, (f16)v2, (f16)v3};
          *(f16x4*)(kb + (bh * 1088 + ni) * 32 + (r - 32)) = pk;
        } else {
          f16* vp = vt + (bh * 64 + (r - 64)) * 1088 + ni;
          vp[0]        = (f16)v0;
          vp[1088]     = (f16)v1;
          vp[2 * 1088] = (f16)v2;
          vp[3 * 1088] = (f16)v3;
        }
      }
    }
  }
}

// ---------------------------------------------------------------------------
// depthwise conv branch (round-3/6 verbatim)
// ---------------------------------------------------------------------------
__global__ __launch_bounds__(256) void conv_kernel(
    const f16* __restrict__ vt, const float* __restrict__ conv_w,
    const float* __restrict__ conv_b, f16* __restrict__ vcT)
{
  __shared__ f16 img[16][34][36];
  const int b = blockIdx.y, g = blockIdx.x;
  const int c0 = g * 16, h = c0 >> 6, ci0 = c0 & 63;
  const int t = threadIdx.x;
  for (int i = t; i < 16 * 34 * 36; i += 256) ((f16*)img)[i] = (f16)0.f;
  __syncthreads();
  const int d = t >> 2, seg = t & 3;
  const f16* src = vt + ((long)(b * 8 + h) * 64 + d) * 1088 + ci0 * 16 + seg * 64;
  const int dhib = d >> 5;
  const int s2 = d & 31;
  #pragma unroll
  for (int j = 0; j < 8; ++j) {
    f16x8 vv = *(const f16x8*)(src + j * 8);
    #pragma unroll
    for (int e = 0; e < 8; ++e) {
      int local = seg * 64 + j * 8 + e;
      int cl = local >> 4, rr = local & 15;
      float xv = (float)vv[e];
      float hs = xv * fminf(fmaxf(xv + 3.f, 0.f), 6.f) * (1.f / 6.f);
      img[cl][1 + rr * 2 + dhib][1 + s2] = (f16)hs;
    }
  }
  __syncthreads();
  const int cl = t & 15, pg = t >> 4;
  const int c = c0 + cl;
  float w[9];
  #pragma unroll
  for (int i = 0; i < 9; ++i) w[i] = conv_w[c * 9 + i];
  const float bias = conv_b[c];
  for (int i = 0; i < 64; ++i) {
    int p = pg + i * 16;
    int s1 = p >> 5, ss2 = p & 31;
    float a = bias;
    #pragma unroll
    for (int di = 0; di < 3; ++di)
      #pragma unroll
      for (int dj = 0; dj < 3; ++dj)
        a += w[di * 3 + dj] * (float)img[cl][s1 + di][ss2 + dj];
    vcT[((long)b * 1024 + p) * 512 + c] = (f16)a;
  }
}

// ---------------------------------------------------------------------------
// fused attention (round-3/6 verbatim)
// ---------------------------------------------------------------------------
__global__ __launch_bounds__(256) void attn_kernel(
    const f16* __restrict__ qb, const f16* __restrict__ kb,
    const f16* __restrict__ vt, f16* __restrict__ opad)
{
  __shared__ f16 kls[2][4 * 64 * 8];
  __shared__ f16 vls[2][8 * 64 * 8];
  __shared__ float l_sh[4][32];

  const int id = blockIdx.x + blockIdx.y * 9;
  const int xcd = id & 7, sl = id >> 3;
  const int bh = xcd * 16 + sl / 9, qblk = sl % 9;
  const int b = bh >> 3, h = bh & 7;
  const int t = threadIdx.x;
  const int wave = t >> 6, lane = t & 63;
  const int lq = lane & 31, hi = lane >> 5;
  const int q0 = qblk * 128 + wave * 32;

  const f16* qb_ = qb + (long)bh * 1152 * 32;
  const f16* kb_ = kb + (long)bh * 1088 * 32;
  const f16* vt_ = vt + (long)bh * 64 * 1088;

  const f16x8 qf0 = *(const f16x8*)(qb_ + (long)(q0 + lq) * 32 + hi * 8);
  const f16x8 qf1 = *(const f16x8*)(qb_ + (long)(q0 + lq) * 32 + 16 + hi * 8);

  const int sk_k = t >> 2, sk_s = t & 3;
  const int sv_d = t >> 3, sv_p = t & 7;
  const int wkoff  = (sk_s * 64 + ((sk_k + sk_s) & 63)) * 16;
  const int wvoff0 = (sv_p * 64 + ((sv_d + sv_p) & 63)) * 16;
  const int wvoff1 = (sv_p * 64 + ((sv_d + 32 + sv_p) & 63)) * 16;
  int koff[2][2], voff[2][4];
  #pragma unroll
  for (int blk = 0; blk < 2; ++blk)
    #pragma unroll
    for (int ss = 0; ss < 2; ++ss) {
      int ss2 = 2 * ss + hi;
      koff[blk][ss] = (ss2 * 64 + ((blk * 32 + lq + ss2) & 63)) * 16;
    }
  #pragma unroll
  for (int nd = 0; nd < 2; ++nd)
    #pragma unroll
    for (int ks = 0; ks < 4; ++ks) {
      int kk8 = 2 * ks + hi;
      voff[nd][ks] = (kk8 * 64 + ((nd * 32 + lq + kk8) & 63)) * 16;
    }

  f16x8 stk, stv0, stv1;
  auto load_tile = [&](int kt) {
    stk  = *(const f16x8*)(kb_ + (long)(kt * 64 + sk_k) * 32 + sk_s * 8);
    stv0 = *(const f16x8*)(vt_ + (long)sv_d * 1088 + kt * 64 + sv_p * 8);
    stv1 = *(const f16x8*)(vt_ + (long)(sv_d + 32) * 1088 + kt * 64 + sv_p * 8);
  };
  auto write_tile = [&](int buf) {
    *(f16x8*)((char*)kls[buf] + wkoff)  = stk;
    *(f16x8*)((char*)vls[buf] + wvoff0) = stv0;
    *(f16x8*)((char*)vls[buf] + wvoff1) = stv1;
  };

  f32x16 o0 = zero16(), o1 = zero16();
  float lsum = 0.f;

  load_tile(0);
  write_tile(0);
  __syncthreads();

  int cur = 0;
  #pragma unroll 1
  for (int kt = 0; kt < 17; ++kt) {
    if (kt < 16) load_tile(kt + 1);
    const char* kcur = (const char*)kls[cur];
    const char* vcur = (const char*)vls[cur];
    f16x8 kf[2][2];
    #pragma unroll
    for (int blk = 0; blk < 2; ++blk)
      #pragma unroll
      for (int ss = 0; ss < 2; ++ss)
        kf[blk][ss] = *(const f16x8*)(kcur + koff[blk][ss]);
    f32x16 s0 = zero16(), s1 = zero16();
    s0 = __builtin_amdgcn_mfma_f32_32x32x16_f16(kf[0][0], qf0, s0, 0, 0, 0);
    s0 = __builtin_amdgcn_mfma_f32_32x32x16_f16(kf[0][1], qf1, s0, 0, 0, 0);
    s1 = __builtin_amdgcn_mfma_f32_32x32x16_f16(kf[1][0], qf0, s1, 0, 0, 0);
    s1 = __builtin_amdgcn_mfma_f32_32x32x16_f16(kf[1][1], qf1, s1, 0, 0, 0);
    float p0[16], p1[16];
    #pragma unroll
    for (int r = 0; r < 16; ++r) { p0[r] = EXP2(s0[r]); p1[r] = EXP2(s1[r]); }
    if (kt == 16) {
      #pragma unroll
      for (int r = 0; r < 16; ++r) {
        int cr = (r & 3) + 8 * (r >> 2) + 4 * hi;
        p0[r] = (cr < 20) ? p0[r] : 0.f;
        p1[r] = 0.f;
      }
    }
    float t8[8];
    #pragma unroll
    for (int r = 0; r < 8; ++r) t8[r] = (p0[r] + p0[r + 8]) + (p1[r] + p1[r + 8]);
    lsum += ((t8[0] + t8[1]) + (t8[2] + t8[3])) + ((t8[4] + t8[5]) + (t8[6] + t8[7]));
    f16x8 pa[4];
    pack_block(p0, pa[0], pa[1]);
    pack_block(p1, pa[2], pa[3]);
    #pragma unroll
    for (int ks = 0; ks < 4; ++ks) {
      f16x8 vf0 = *(const f16x8*)(vcur + voff[0][ks]);
      f16x8 vf1 = *(const f16x8*)(vcur + voff[1][ks]);
      o0 = __builtin_amdgcn_mfma_f32_32x32x16_f16(pa[ks], vf0, o0, 0, 0, 0);
      o1 = __builtin_amdgcn_mfma_f32_32x32x16_f16(pa[ks], vf1, o1, 0, 0, 0);
    }
    if (kt < 16) write_tile(cur ^ 1);
    __syncthreads();
    cur ^= 1;
  }

  lsum += __shfl_xor(lsum, 32);
  l_sh[wave][lq] = lsum;
  __syncthreads();
  float invl[16];
  #pragma unroll
  for (int r = 0; r < 16; ++r) {
    int cr = (r & 3) + 8 * (r >> 2) + 4 * hi;
    invl[r] = __builtin_amdgcn_rcpf(l_sh[wave][cr]);
  }
  #pragma unroll
  for (int nd = 0; nd < 2; ++nd) {
    #pragma unroll
    for (int r = 0; r < 16; ++r) {
      int cr = (r & 3) + 8 * (r >> 2) + 4 * hi;
      int q = q0 + cr;
      if (q < 1044) {
        float val = (nd ? o1[r] : o0[r]) * invl[r];
        unsigned flat = (unsigned)q * 512u + (unsigned)h * 64u + (unsigned)(nd * 32 + lq);
        unsigned c = flat / 1044u;
        unsigned np = flat - c * 1044u;
        opad[((long)b * 512 + c) * 1056 + np] = (f16)val;
      }
    }
  }
}

// ---------------------------------------------------------------------------
// proj GEMM (round-7 verbatim; extra clamp arg).  grid dim3(4,8,16)
// ---------------------------------------------------------------------------
__global__ __launch_bounds__(256) void proj_gemm(
    const f16* __restrict__ pw, const f16* __restrict__ opad,
    const float* __restrict__ proj_b, const f16* __restrict__ vcT,
    f16* __restrict__ xoT)
{
  __shared__ f16 As[128 * 40];
  __shared__ f16 Bs[128 * 40];
  const int id = blockIdx.x + blockIdx.y * 4 + blockIdx.z * 32;  // [0,512)
  const int lin = (id & 7) * 64 + (id >> 3);                     // bijective
  const int b = lin >> 5;
  const int rc = lin & 31;
  const int row0 = (rc >> 2) * 128;  // m (image pixel)
  const int col0 = (rc & 3) * 128;   // c (channel)
  f32x4 acc[4][4];
  #pragma unroll
  for (int m = 0; m < 4; ++m)
    #pragma unroll
    for (int n = 0; n < 4; ++n) acc[m][n] = (f32x4){0.f, 0.f, 0.f, 0.f};
  gemm_core(pw + (long)row0 * 1056, opad + ((long)b * 512 + col0) * 1056,
            1056, 1056, 33, 1 << 30, 1 << 30, As, Bs, acc);
  const int lane = threadIdx.x & 63, wave = threadIdx.x >> 6;
  const int wr = wave >> 1, wc = wave & 1, fr = lane & 15, fg = lane >> 4;
  #pragma unroll
  for (int m = 0; m < 4; ++m) {
    #pragma unroll
    for (int rr = 0; rr < 4; ++rr) {
      int mi = row0 + wr * 64 + m * 16 + fg * 4 + rr;
      float pb = proj_b[mi];
      #pragma unroll
      for (int n = 0; n < 4; ++n) {
        int c = col0 + wc * 64 + n * 16 + fr;
        long idx = ((long)b * 1024 + mi) * 512 + c;
        xoT[idx] = (f16)(acc[m][n][rr] + pb + (float)vcT[idx]);
      }
    }
  }
}

// ---------------------------------------------------------------------------
// out GEMM (round-7 verbatim; extra clamp arg).  grid dim3(4,8,16)
// ---------------------------------------------------------------------------
__global__ __launch_bounds__(256) void out_gemm(
    const f16* __restrict__ xoT, const f16* __restrict__ ow,
    const float* __restrict__ out_b, float* __restrict__ out)
{
  __shared__ f16 As[128 * 40];
  __shared__ f16 Bs[128 * 40];
  const int id = blockIdx.x + blockIdx.y * 4 + blockIdx.z * 32;  // [0,512)
  const int lin = (id & 7) * 64 + (id >> 3);                     // bijective
  const int b = lin >> 5;
  const int rc = lin & 31;
  const int row0 = (rc >> 2) * 128;
  const int col0 = (rc & 3) * 128;
  f32x4 acc[4][4];
  #pragma unroll
  for (int m = 0; m < 4; ++m)
    #pragma unroll
    for (int n = 0; n < 4; ++n) acc[m][n] = (f32x4){0.f, 0.f, 0.f, 0.f};
  gemm_core(xoT + ((long)b * 1024 + row0) * 512, ow + (long)col0 * 512,
            512, 512, 16, 1 << 30, 1 << 30, As, Bs, acc);
  const int lane = threadIdx.x & 63, wave = threadIdx.x >> 6;
  const int wr = wave >> 1, wc = wave & 1, fr = lane & 15, fg = lane >> 4;
  float ob[4];
  #pragma unroll
  for (int n = 0; n < 4; ++n) ob[n] = out_b[col0 + wc * 64 + n * 16 + fr];
  #pragma unroll
  for (int m = 0; m < 4; ++m) {
    #pragma unroll
    for (int rr = 0; rr < 4; ++rr) {
      int mi = row0 + wr * 64 + m * 16 + fg * 4 + rr;
      #pragma unroll
      for (int n = 0; n < 4; ++n) {
        int co = col0 + wc * 64 + n * 16 + fr;
        out[((long)b * 1024 + mi) * 512 + co] = acc[m][n][rr] + ob[n];
      }
    }
  }
}

// ---------------------------------------------------------------------------
extern "C" void kernel_launch(void* const* d_in, const int* in_sizes, int n_in,
                              void* d_out, int out_size, void* d_ws, size_t ws_size,
                              hipStream_t stream) {
  const float* x      = (const float*)d_in[0];
  const float* qkv_w  = (const float*)d_in[1];
  const float* bn_g   = (const float*)d_in[2];
  const float* bn_b   = (const float*)d_in[3];
  const float* bn_m   = (const float*)d_in[4];
  const float* bn_v   = (const float*)d_in[5];
  const float* conv_w = (const float*)d_in[6];
  const float* conv_b = (const float*)d_in[7];
  const float* proj_w = (const float*)d_in[8];
  const float* proj_b = (const float*)d_in[9];
  const float* out_w  = (const float*)d_in[10];
  const float* out_b  = (const float*)d_in[11];
  float* out = (float*)d_out;

  char* ws = (char*)d_ws;
  f16*   x_h   = (f16*)(ws + OFF_XH);
  f16*   wq_h  = (f16*)(ws + OFF_WQ);
  f16*   pw_h  = (f16*)(ws + OFF_PW);
  f16*   ow_h  = (f16*)(ws + OFF_OW);
  float* bn_a  = (float*)(ws + OFF_BNA);
  float* bn_sh = (float*)(ws + OFF_BNB);
  f16*   qb    = (f16*)(ws + OFF_QB);
  f16*   kb    = (f16*)(ws + OFF_KB);
  f16*   vt    = (f16*)(ws + OFF_VT);
  f16*   opad  = (f16*)(ws + OFF_OPAD);
  f16*   vcT   = (f16*)(ws + OFF_VCT);
  f16*   xoT   = (f16*)(ws + OFF_XOT);

  prep_kernel<<<1024, 256, 0, stream>>>(x, qkv_w, bn_g, bn_b, bn_m, bn_v,
                                        proj_w, out_w, x_h, wq_h, pw_h, ow_h,
                                        bn_a, bn_sh, qb, kb, vt, opad);
  qkv_gemm<<<dim3(8, 131), 256, 0, stream>>>(x_h, wq_h, bn_a, bn_sh, qb, kb, vt);
  conv_kernel<<<dim3(32, 16), 256, 0, stream>>>(vt, conv_w, conv_b, vcT);
  attn_kernel<<<dim3(9, 128), 256, 0, stream>>>(qb, kb, vt, opad);
  proj_gemm<<<dim3(4, 8, 16), 256, 0, stream>>>(pw_h, opad, proj_b, vcT, xoT);
  out_gemm<<<dim3(4, 8, 16), 256, 0, stream>>>(xoT, ow_h, out_b, out);
}